// Round 6
// baseline (1687.158 us; speedup 1.0000x reference)
//
#include <hip/hip_runtime.h>
#include <math.h>
#include <stdint.h>

#define NTOK 4096
#define DIM  1024
#define NCOL 65536
#define RANK 128
#define CK 20
#define FK 10

// ---- Path A (MFMA) geometry ----
#define SLABS 16
#define SLABCOLS (NCOL / SLABS)      // 4096
#define BM 128
#define BN 256
#define BK 32
#define NCHUNK (SLABCOLS / BN)       // 16
#define KSTEPS (DIM / BK)            // 32
#define CKS 12                       // per-slab list length
#define NPART (SLABS * CKS)          // 192
#define POOL 32
#define BUFSZ 24576                  // A 8KB + B 16KB
#define SELSTRIDE 132                // f32; rows 528B (16B-aligned); 2-way banks

typedef _Float16 f16;
typedef __attribute__((ext_vector_type(8))) _Float16 f16x8;
typedef __attribute__((ext_vector_type(4))) float f32x4;

__device__ __forceinline__ void f32_split(float v, unsigned short& h, unsigned short& l) {
    f16 hh = (f16)v;
    float r = v - (float)hh;
    f16 ll = (f16)r;
    h = __builtin_bit_cast(unsigned short, hh);
    l = __builtin_bit_cast(unsigned short, ll);
}

__device__ __forceinline__ void gll16(const void* src, void* ldsdst) {
    __builtin_amdgcn_global_load_lds(
        (__attribute__((address_space(1))) unsigned int*)src,
        (__attribute__((address_space(3))) unsigned int*)ldsdst, 16, 0, 0);
}

#define WAITVM_(n) asm volatile("s_waitcnt vmcnt(" #n ")" ::: "memory")
#define WAITLGKM0  asm volatile("s_waitcnt lgkmcnt(0)" ::: "memory")

// ---------------------------------------------------------------------------
// K0x: x -> f16 hi plane only (A operand), layout [t][k]
// ---------------------------------------------------------------------------
__global__ __launch_bounds__(256)
void k0_convx(const float* __restrict__ x, unsigned short* __restrict__ xh)
{
    int i = blockIdx.x * 256 + threadIdx.x;   // float4 index
    float4 v = ((const float4*)x)[i];
    ushort4 h; unsigned short dummy;
    f32_split(v.x, h.x, dummy); f32_split(v.y, h.y, dummy);
    f32_split(v.z, h.z, dummy); f32_split(v.w, h.w, dummy);
    ((ushort4*)xh)[i] = h;
}

// ---------------------------------------------------------------------------
// K0w: W[k][n] f32 -> WhT[n][k], WlT[n][k]  (f16 bits, scaled x1024), 64x64 tiles
// ---------------------------------------------------------------------------
__global__ __launch_bounds__(256)
void k0_convw(const float* __restrict__ W, unsigned short* __restrict__ WhT,
              unsigned short* __restrict__ WlT)
{
    __shared__ float t[64][65];
    const int tid = threadIdx.x;
    const int k0 = blockIdx.x * 64;
    const int n0 = blockIdx.y * 64;
#pragma unroll
    for (int i = 0; i < 16; ++i) {
        int idx = i * 256 + tid;
        int r = idx >> 6, c = idx & 63;
        t[r][c] = W[(size_t)(k0 + r) * NCOL + n0 + c];
    }
    __syncthreads();
#pragma unroll
    for (int i = 0; i < 8; ++i) {
        int idx = i * 256 + tid;
        int n = idx >> 5, kp = idx & 31;
        float a = t[2 * kp][n]     * 1024.0f;
        float b = t[2 * kp + 1][n] * 1024.0f;
        unsigned short ah, al, bh, bl;
        f32_split(a, ah, al);
        f32_split(b, bh, bl);
        unsigned int wh = (unsigned)ah | ((unsigned)bh << 16);
        unsigned int wl = (unsigned)al | ((unsigned)bl << 16);
        size_t row = (size_t)(n0 + n) * DIM + k0;
        *(unsigned int*)(WhT + row + 2 * kp) = wh;
        *(unsigned int*)(WlT + row + 2 * kp) = wl;
    }
}

// ---------------------------------------------------------------------------
// K1: f16 MFMA approx logits + fused per-(token, slab) top-12.
// 512 thr (8 waves, 2x4 of 64x64 tiles), tile 128 tok x 256 cols/chunk, BK=32.
// 3 staging buffers (24KB, conflict-free swizzle), SINGLE barrier per K-step
// (3-buffer depth makes the trailing barrier redundant), counted vmcnt(3).
// 72KB LDS -> 2 blocks/CU; float4+max-tree scan.
// ---------------------------------------------------------------------------
__global__ __launch_bounds__(512, 4)
void k1_mfma(const unsigned short* __restrict__ xh,
             const unsigned short* __restrict__ WhT,
             float* __restrict__ part_s, int* __restrict__ part_i)
{
    // 3 staging buffers @ b*24576: A[128][32]f16 (8KB) + B[256][32]f16 (16KB)
    // swizzle: LDS slot (row, j) holds global k-octet j ^ ((row>>1)&3)
    // sel f32[128][132] (67.6KB) aliases staging (dead during selection)
    // merge lists @ 0 / 24576 after all chunks done
    __shared__ __align__(16) unsigned char smem[73728];

    const int tid  = threadIdx.x;
    const int lane = tid & 63;
    const int wave = tid >> 6;
    const int wr = wave >> 2;        // 0..1 : 64-row half
    const int wc = wave & 3;         // 0..3 : 64-col group
    const int slab = blockIdx.x;     // 0..15
    const int tokbase = blockIdx.y * BM;

    // staging: thread covers (row = tid>>2, slot = tid&3); global oct pre-swizzled
    const int srow = tid >> 2;
    const int soct = (tid & 3) ^ ((tid >> 3) & 3);   // (tid&3) ^ ((row>>1)&3)
    const unsigned short* pA = xh + (size_t)(tokbase + srow) * DIM + soct * 8;

    // frag reads: row&? -> slot = (lane>>4) ^ ((c4>>1)&3)  [row = ..*16 + c4]
    const int c4 = lane & 15;
    const int xj = (((lane >> 4) ^ ((c4 >> 1) & 3)) << 4);
    const int offA0 =        (wr * 64 + c4) * 64 + xj;   // + m*1024
    const int offB0 = 8192 + (wc * 64 + c4) * 64 + xj;   // + n*1024

    float ts[CKS]; int ti[CKS];
#pragma unroll
    for (int k = 0; k < CKS; ++k) { ts[k] = -INFINITY; ti[k] = 0x7fffffff; }
    const int tok_sel = tid >> 2;    // 0..127
    const int part    = tid & 3;     // 16-col window

    float* sel = (float*)smem;

    #define STAGE(pb, buf, kk) do {                                              \
        unsigned b_ = (unsigned)(buf) * 24576u + (unsigned)wave * 1024u;         \
        gll16(pA   + (size_t)(kk) * BK,                smem + b_);               \
        gll16((pb) + (size_t)(kk) * BK,                smem + b_ + 8192);        \
        gll16((pb) + (size_t)128 * DIM + (kk) * BK,    smem + b_ + 16384);       \
    } while (0)

    #define SCAN16(ibase_, rp_) do {                                             \
        _Pragma("unroll")                                                         \
        for (int j = 0; j < 4; ++j) {                                             \
            float4 v = *(const float4*)((rp_) + 4 * j);                           \
            float m01 = fmaxf(v.x, v.y), m23 = fmaxf(v.z, v.w);                   \
            if (fmaxf(m01, m23) > ts[CKS - 1]) {                                  \
                float vv[4] = {v.x, v.y, v.z, v.w};                               \
                _Pragma("unroll")                                                 \
                for (int e = 0; e < 4; ++e) {                                     \
                    float cv = vv[e];                                             \
                    if (cv > ts[CKS - 1]) {                                       \
                        int ci = (ibase_) + 4 * j + e;                            \
                        _Pragma("unroll")                                         \
                        for (int k = 0; k < CKS; ++k) {                           \
                            bool g = cv > ts[k];                                  \
                            float os = ts[k]; int oi = ti[k];                     \
                            ts[k] = g ? cv : os; ti[k] = g ? ci : oi;             \
                            cv = g ? os : cv;   ci = g ? oi : ci;                 \
                        }                                                         \
                    }                                                             \
                }                                                                 \
            }                                                                     \
        }                                                                         \
    } while (0)

#pragma unroll 1
    for (int nc = 0; nc < NCHUNK; ++nc) {
        const int n0 = slab * SLABCOLS + nc * BN;
        const unsigned short* pB = WhT + (size_t)(n0 + srow) * DIM + soct * 8;

        f32x4 acc[4][4];
        const f32x4 zero = {0.f, 0.f, 0.f, 0.f};
#pragma unroll
        for (int m = 0; m < 4; ++m)
#pragma unroll
            for (int n = 0; n < 4; ++n) acc[m][n] = zero;

        STAGE(pB, 0, 0);
        STAGE(pB, 1, 1);

#pragma unroll 1
        for (int kk = 0; kk < KSTEPS; ++kk) {
            if (kk < KSTEPS - 1) {
                WAITVM_(3);                  // stage kk landed (oldest 3 retired)
            } else {
                WAITVM_(0);
            }
            __builtin_amdgcn_s_barrier();    // all waves' stage-kk visible; prev reads done

            if (kk + 2 < KSTEPS) STAGE(pB, (kk + 2) % 3, kk + 2);

            const unsigned char* bp = smem + (unsigned)(kk % 3) * 24576u;
            f16x8 Af[4];
#pragma unroll
            for (int m = 0; m < 4; ++m) Af[m] = *(const f16x8*)(bp + offA0 + m * 1024);
#pragma unroll
            for (int n = 0; n < 4; ++n) {
                f16x8 Bf = *(const f16x8*)(bp + offB0 + n * 1024);
#pragma unroll
                for (int m = 0; m < 4; ++m)
                    acc[m][n] = __builtin_amdgcn_mfma_f32_16x16x32_f16(Af[m], Bf, acc[m][n], 0, 0, 0);
            }

            WAITLGKM0;                       // my frag reads done before next top barrier
        }
        __builtin_amdgcn_s_barrier();        // K-loop fully done before sel overwrites staging

        // ---- selection: 2 phases of 128 cols; float4 + max-tree scan ----
#pragma unroll 1
        for (int p = 0; p < 2; ++p) {
            if ((wc >> 1) == p) {
                const int colb = (wc & 1) * 64;
#pragma unroll
                for (int m = 0; m < 4; ++m)
#pragma unroll
                    for (int n = 0; n < 4; ++n) {
                        const int col = colb + n * 16 + c4;
                        const int row = wr * 64 + m * 16 + (lane >> 4) * 4;
#pragma unroll
                        for (int r = 0; r < 4; ++r)
                            sel[(row + r) * SELSTRIDE + col] = acc[m][n][r];
                    }
            }
            __syncthreads();
            {
                const float* rp = sel + tok_sel * SELSTRIDE;
                SCAN16(n0 + p * 128 +      part * 16, rp +      part * 16);
                SCAN16(n0 + p * 128 + 64 + part * 16, rp + 64 + part * 16);
            }
            __syncthreads();
        }
    }
    #undef STAGE

    // ---- merge the 4 per-part lists per token -> slab top-12 ----
    float* Ls = (float*)smem;                 // 512*12*4 = 24576
    int*   Li = (int*)(smem + 24576);
#pragma unroll
    for (int k = 0; k < CKS; ++k) {
        Ls[tid * CKS + k] = ts[k];
        Li[tid * CKS + k] = ti[k];
    }
    __syncthreads();
    if (tid < BM) {
        const int b0 = (tid * 4 + 0) * CKS, b1 = (tid * 4 + 1) * CKS;
        const int b2 = (tid * 4 + 2) * CKS, b3 = (tid * 4 + 3) * CKS;
        int h0 = 0, h1 = 0, h2 = 0, h3 = 0;
        const size_t ob = ((size_t)(tokbase + tid) * SLABS + slab) * CKS;
#pragma unroll 1
        for (int k = 0; k < CKS; ++k) {
            float s0 = Ls[b0 + h0]; int i0 = Li[b0 + h0];
            float s1 = Ls[b1 + h1]; int i1 = Li[b1 + h1];
            float s2 = Ls[b2 + h2]; int i2 = Li[b2 + h2];
            float s3 = Ls[b3 + h3]; int i3 = Li[b3 + h3];
            float bs = s0; int bi = i0; int bp = 0;
            if (s1 > bs || (s1 == bs && i1 < bi)) { bs = s1; bi = i1; bp = 1; }
            if (s2 > bs || (s2 == bs && i2 < bi)) { bs = s2; bi = i2; bp = 2; }
            if (s3 > bs || (s3 == bs && i3 < bi)) { bs = s3; bi = i3; bp = 3; }
            part_s[ob + k] = bs; part_i[ob + k] = bi;
            if      (bp == 0) ++h0;
            else if (bp == 1) ++h1;
            else if (bp == 2) ++h2;
            else              ++h3;
        }
    }
}

// ---------------------------------------------------------------------------
// K3: merge 192 approx partials -> approx top-32 pool -> exact rescore
// (f32 x, split-f16 W reconstruction) -> exact top-20 -> fine stage.
// ---------------------------------------------------------------------------
__global__ __launch_bounds__(256)
void k3_fine(const float* __restrict__ x, const float* __restrict__ Wenc,
             const float* __restrict__ Kall, const float* __restrict__ Vall,
             const unsigned short* __restrict__ WhT, const unsigned short* __restrict__ WlT,
             const float* __restrict__ part_s, const int* __restrict__ part_i,
             float* __restrict__ out)
{
    const int tok = blockIdx.x;
    const int tid = threadIdx.x;

    __shared__ float xs[DIM];
    __shared__ float qs[RANK];
    __shared__ float ls[NPART];
    __shared__ int   li[NPART];
    __shared__ int   pool[POOL];
    __shared__ float resc[POOL];
    __shared__ int   cand[CK];
    __shared__ float fsc[CK];
    __shared__ float fss[FK];
    __shared__ int   fgi[FK];
    __shared__ float fw[FK];

    ((float4*)xs)[tid] = ((const float4*)(x + (size_t)tok * DIM))[tid];
    if (tid < NPART) {
        ls[tid] = part_s[(size_t)tok * NPART + tid];
        li[tid] = part_i[(size_t)tok * NPART + tid];
    }
    __syncthreads();

    // approx top-32 of 192 via lex rank (idx distinct -> unique ranks)
    if (tid < NPART) {
        float s = ls[tid]; int idx = li[tid];
        int r = 0;
        for (int e = 0; e < NPART; ++e) {
            float s2 = ls[e]; int i2 = li[e];
            r += (s2 > s) || (s2 == s && i2 < idx);
        }
        if (r < POOL) pool[r] = idx;
    }
    __syncthreads();

    // exact rescore of 32 pooled candidates: 8 threads per candidate
    {
        const int c = tid >> 3, oct = tid & 7;
        const int idx = pool[c];
        const ushort4* ph = (const ushort4*)(WhT + (size_t)idx * DIM + oct * 128);
        const ushort4* pl = (const ushort4*)(WlT + (size_t)idx * DIM + oct * 128);
        const float* xp = xs + oct * 128;
        float a = 0.0f;
#pragma unroll 4
        for (int j = 0; j < 32; ++j) {
            ushort4 hv = ph[j], lv = pl[j];
            a = fmaf(xp[j*4+0], (float)__builtin_bit_cast(f16, hv.x) + (float)__builtin_bit_cast(f16, lv.x), a);
            a = fmaf(xp[j*4+1], (float)__builtin_bit_cast(f16, hv.y) + (float)__builtin_bit_cast(f16, lv.y), a);
            a = fmaf(xp[j*4+2], (float)__builtin_bit_cast(f16, hv.z) + (float)__builtin_bit_cast(f16, lv.z), a);
            a = fmaf(xp[j*4+3], (float)__builtin_bit_cast(f16, hv.w) + (float)__builtin_bit_cast(f16, lv.w), a);
        }
        a += __shfl_down(a, 4, 8);
        a += __shfl_down(a, 2, 8);
        a += __shfl_down(a, 1, 8);
        if (oct == 0) resc[c] = a * (1.0f / 1024.0f);   // undo x1024 W scale (exact)
    }
    __syncthreads();

    // exact top-20 of 32 rescored (lex: score desc, idx asc)
    if (tid < POOL) {
        float s = resc[tid]; int idx = pool[tid];
        int r = 0;
        for (int e = 0; e < POOL; ++e)
            r += (resc[e] > s) || (resc[e] == s && pool[e] < idx);
        if (r < CK) cand[r] = idx;
    }
    __syncthreads();

    // query = x . W_enc
    if (tid < RANK) {
        float q = 0.0f;
#pragma unroll 8
        for (int d = 0; d < DIM; ++d)
            q = fmaf(xs[d], Wenc[(size_t)d * RANK + tid], q);
        qs[tid] = q;
    }
    __syncthreads();

    if (tid < CK) {
        const float* Kr = Kall + (size_t)cand[tid] * RANK;
        float s = 0.0f;
#pragma unroll 8
        for (int r = 0; r < RANK; ++r) s = fmaf(qs[r], Kr[r], s);
        fsc[tid] = s * 0.08838834764831845f;   // 1/sqrt(128)
    }
    __syncthreads();

    if (tid < CK) {
        float s = fsc[tid]; int r = 0;
        for (int e = 0; e < CK; ++e)
            r += (fsc[e] > s) || (fsc[e] == s && e < tid);
        if (r < FK) { fss[r] = s; fgi[r] = cand[tid]; }
    }
    __syncthreads();

    if (tid == 0) {
        float m = fss[0];
#pragma unroll
        for (int k = 1; k < FK; ++k) m = fmaxf(m, fss[k]);
        float w[FK]; float sum = 0.0f;
#pragma unroll
        for (int k = 0; k < FK; ++k) { w[k] = expf(fss[k] - m); sum += w[k]; }
        float inv = 1.0f / sum;
#pragma unroll
        for (int k = 0; k < FK; ++k) fw[k] = w[k] * inv;
    }
    __syncthreads();

#pragma unroll
    for (int jj = 0; jj < DIM / 256; ++jj) {
        const int d = tid + jj * 256;
        float o = 0.0f;
#pragma unroll
        for (int f = 0; f < FK; ++f)
            o = fmaf(fw[f], Vall[(size_t)fgi[f] * DIM + d], o);
        out[(size_t)tok * DIM + d] = o;
    }
}

// ---------------------------------------------------------------------------
// Fallback path (round-1, f32 VALU): proven correct if ws is too small.
// ---------------------------------------------------------------------------
__global__ __launch_bounds__(256, 2)
void k1_router_f32(const float* __restrict__ x, const float* __restrict__ Wr,
                   float* __restrict__ part_s, int* __restrict__ part_i)
{
    __shared__ float smem[64][257];
    const int tid     = threadIdx.x;
    const int tokbase = blockIdx.x * 64;
    const int colbase = blockIdx.y * 8192;
    const int mytok   = tid & 63;
    const int mypart  = tid >> 6;

    float ts[CK]; int ti[CK];
#pragma unroll
    for (int k = 0; k < CK; ++k) { ts[k] = -INFINITY; ti[k] = 0x7fffffff; }

#pragma unroll 1
    for (int cg = 0; cg < 32; ++cg) {
        const int n = colbase + cg * 256 + tid;
        float acc[64];
#pragma unroll
        for (int t = 0; t < 64; ++t) acc[t] = 0.0f;
#pragma unroll 1
        for (int dc = 0; dc < DIM; dc += 8) {
            float w[8];
#pragma unroll
            for (int i = 0; i < 8; ++i)
                w[i] = Wr[(size_t)(dc + i) * NCOL + n];
#pragma unroll
            for (int t = 0; t < 64; ++t) {
                const float* xr = x + (size_t)(tokbase + t) * DIM + dc;
#pragma unroll
                for (int i = 0; i < 8; ++i)
                    acc[t] = fmaf(xr[i], w[i], acc[t]);
            }
        }
        __syncthreads();
#pragma unroll
        for (int t = 0; t < 64; ++t) smem[t][tid] = acc[t];
        __syncthreads();
        const int jbase = mypart * 64;
#pragma unroll 1
        for (int j = 0; j < 64; ++j) {
            float v = smem[mytok][jbase + j];
            if (v > ts[CK - 1]) {
                float cv = v; int ci = colbase + cg * 256 + jbase + j;
#pragma unroll
                for (int k = 0; k < CK; ++k) {
                    bool g = cv > ts[k];
                    float os = ts[k]; int oi = ti[k];
                    ts[k] = g ? cv : os; ti[k] = g ? ci : oi;
                    cv = g ? os : cv;   ci = g ? oi : ci;
                }
            }
        }
    }
    __syncthreads();
    float* Ls = &smem[0][0];
    int*   Li = (int*)(Ls + 256 * CK);
#pragma unroll
    for (int k = 0; k < CK; ++k) { Ls[tid * CK + k] = ts[k]; Li[tid * CK + k] = ti[k]; }
    __syncthreads();
    if (tid < 64) {
        const int tok = tid;
        int h0 = 0, h1 = 0, h2 = 0, h3 = 0;
        const size_t ob = ((size_t)(tokbase + tok) * 8 + blockIdx.y) * CK;
#pragma unroll 1
        for (int k = 0; k < CK; ++k) {
            float s0 = Ls[(      tok) * CK + h0]; int i0 = Li[(      tok) * CK + h0];
            float s1 = Ls[( 64 + tok) * CK + h1]; int i1 = Li[( 64 + tok) * CK + h1];
            float s2 = Ls[(128 + tok) * CK + h2]; int i2 = Li[(128 + tok) * CK + h2];
            float s3 = Ls[(192 + tok) * CK + h3]; int i3 = Li[(192 + tok) * CK + h3];
            float bs = s0; int bi = i0; int bp = 0;
            if (s1 > bs || (s1 == bs && i1 < bi)) { bs = s1; bi = i1; bp = 1; }
            if (s2 > bs || (s2 == bs && i2 < bi)) { bs = s2; bi = i2; bp = 2; }
            if (s3 > bs || (s3 == bs && i3 < bi)) { bs = s3; bi = i3; bp = 3; }
            part_s[ob + k] = bs; part_i[ob + k] = bi;
            if      (bp == 0) ++h0;
            else if (bp == 1) ++h1;
            else if (bp == 2) ++h2;
            else              ++h3;
        }
    }
}

template<int CT, int BLK>
__global__ __launch_bounds__(BLK)
void k3_fine_direct(const float* __restrict__ x, const float* __restrict__ Wenc,
                    const float* __restrict__ Kall, const float* __restrict__ Vall,
                    const float* __restrict__ part_s, const int* __restrict__ part_i,
                    float* __restrict__ out)
{
    const int tok = blockIdx.x;
    const int tid = threadIdx.x;

    __shared__ float xs[DIM];
    __shared__ float qs[RANK];
    __shared__ float ls[CT * CK];
    __shared__ int   li[CT * CK];
    __shared__ int   cand[CK];
    __shared__ float fsc[CK];
    __shared__ float fss[FK];
    __shared__ int   fgi[FK];
    __shared__ float fw[FK];

    if (tid < DIM / 4)
        ((float4*)xs)[tid] = ((const float4*)(x + (size_t)tok * DIM))[tid];
    for (int i = tid; i < CT * CK; i += BLK) {
        ls[i] = part_s[(size_t)tok * (CT * CK) + i];
        li[i] = part_i[(size_t)tok * (CT * CK) + i];
    }
    __syncthreads();

    if (tid < CT * CK) {
        float s = ls[tid]; int idx = li[tid];
        int r = 0;
        for (int e = 0; e < CT * CK; ++e) {
            float s2 = ls[e]; int i2 = li[e];
            r += (s2 > s) || (s2 == s && i2 < idx);
        }
        if (r < CK) cand[r] = idx;
    }
    __syncthreads();

    if (tid < RANK) {
        float q = 0.0f;
#pragma unroll 8
        for (int d = 0; d < DIM; ++d)
            q = fmaf(xs[d], Wenc[(size_t)d * RANK + tid], q);
        qs[tid] = q;
    }
    __syncthreads();

    if (tid < CK) {
        const float* Kr = Kall + (size_t)cand[tid] * RANK;
        float s = 0.0f;
#pragma unroll 8
        for (int r = 0; r < RANK; ++r) s = fmaf(qs[r], Kr[r], s);
        fsc[tid] = s * 0.08838834764831845f;
    }
    __syncthreads();

    if (tid < CK) {
        float s = fsc[tid]; int r = 0;
        for (int e = 0; e < CK; ++e)
            r += (fsc[e] > s) || (fsc[e] == s && e < tid);
        if (r < FK) { fss[r] = s; fgi[r] = cand[tid]; }
    }
    __syncthreads();

    if (tid == 0) {
        float m = fss[0];
#pragma unroll
        for (int k = 1; k < FK; ++k) m = fmaxf(m, fss[k]);
        float w[FK]; float sum = 0.0f;
#pragma unroll
        for (int k = 0; k < FK; ++k) { w[k] = expf(fss[k] - m); sum += w[k]; }
        float inv = 1.0f / sum;
#pragma unroll
        for (int k = 0; k < FK; ++k) fw[k] = w[k] * inv;
    }
    __syncthreads();

    for (int d = tid; d < DIM; d += BLK) {
        float o = 0.0f;
#pragma unroll
        for (int f = 0; f < FK; ++f)
            o = fmaf(fw[f], Vall[(size_t)fgi[f] * DIM + d], o);
        out[(size_t)tok * DIM + d] = o;
    }
}

extern "C" void kernel_launch(void* const* d_in, const int* in_sizes, int n_in,
                              void* d_out, int out_size, void* d_ws, size_t ws_size,
                              hipStream_t stream)
{
    (void)in_sizes; (void)n_in; (void)out_size;
    const float* x    = (const float*)d_in[0];
    const float* Wr   = (const float*)d_in[1];
    const float* Wenc = (const float*)d_in[2];
    const float* Kall = (const float*)d_in[3];
    const float* Vall = (const float*)d_in[4];
    float* out = (float*)d_out;

    const size_t off_ps = 0;
    const size_t off_pi = off_ps + (size_t)NTOK * NPART * 4;
    const size_t off_xh = off_pi + (size_t)NTOK * NPART * 4;
    const size_t off_wh = off_xh + (size_t)NTOK * DIM * 2;
    const size_t off_wl = off_wh + (size_t)NCOL * DIM * 2;
    const size_t REQ    = off_wl + (size_t)NCOL * DIM * 2;   // ~270 MiB

    if (ws_size >= REQ) {
        float* part_s = (float*)((char*)d_ws + off_ps);
        int*   part_i = (int*)((char*)d_ws + off_pi);
        unsigned short* xh  = (unsigned short*)((char*)d_ws + off_xh);
        unsigned short* WhT = (unsigned short*)((char*)d_ws + off_wh);
        unsigned short* WlT = (unsigned short*)((char*)d_ws + off_wl);

        k0_convx<<<NTOK * DIM / 1024, 256, 0, stream>>>(x, xh);
        k0_convw<<<dim3(DIM / 64, NCOL / 64), 256, 0, stream>>>(Wr, WhT, WlT);
        k1_mfma<<<dim3(SLABS, NTOK / BM), 512, 0, stream>>>(xh, WhT, part_s, part_i);
        k3_fine<<<NTOK, 256, 0, stream>>>(x, Wenc, Kall, Vall, WhT, WlT, part_s, part_i, out);
    } else {
        float* part_s = (float*)d_ws;
        int*   part_i = (int*)d_ws + (size_t)NTOK * 8 * CK;
        k1_router_f32<<<dim3(NTOK / 64, 8), 256, 0, stream>>>(x, Wr, part_s, part_i);
        k3_fine_direct<8, 256><<<NTOK, 256, 0, stream>>>(x, Wenc, Kall, Vall, part_s, part_i, out);
    }
}

// Round 7
// 1445.034 us; speedup vs baseline: 1.1676x; 1.1676x over previous
//
#include <hip/hip_runtime.h>
#include <math.h>
#include <stdint.h>

#define NTOK 4096
#define DIM  1024
#define NCOL 65536
#define RANK 128
#define CK 20
#define FK 10

// ---- Path A (MFMA) geometry ----
#define SLABS 16
#define SLABCOLS (NCOL / SLABS)      // 4096
#define BM 128
#define BN 256
#define BK 32
#define NCHUNK (SLABCOLS / BN)       // 16
#define KSTEPS (DIM / BK)            // 32
#define CKS 12                       // per-slab list length
#define NPART (SLABS * CKS)          // 192
#define POOL 32
#define SELSTRIDE 132                // f32; rows 528B; 2-way banks on scan

typedef _Float16 f16;
typedef __attribute__((ext_vector_type(8))) _Float16 f16x8;
typedef __attribute__((ext_vector_type(4))) float f32x4;

__device__ __forceinline__ void f32_split(float v, unsigned short& h, unsigned short& l) {
    f16 hh = (f16)v;
    float r = v - (float)hh;
    f16 ll = (f16)r;
    h = __builtin_bit_cast(unsigned short, hh);
    l = __builtin_bit_cast(unsigned short, ll);
}

__device__ __forceinline__ void gll16(const void* src, void* ldsdst) {
    __builtin_amdgcn_global_load_lds(
        (__attribute__((address_space(1))) unsigned int*)src,
        (__attribute__((address_space(3))) unsigned int*)ldsdst, 16, 0, 0);
}

#define WAITVM_(n) asm volatile("s_waitcnt vmcnt(" #n ")" ::: "memory")
#define WAITLGKM0  asm volatile("s_waitcnt lgkmcnt(0)" ::: "memory")

// ---------------------------------------------------------------------------
// K0x: x -> f16 hi plane only (A operand), layout [t][k]
// ---------------------------------------------------------------------------
__global__ __launch_bounds__(256)
void k0_convx(const float* __restrict__ x, unsigned short* __restrict__ xh)
{
    int i = blockIdx.x * 256 + threadIdx.x;   // float4 index
    float4 v = ((const float4*)x)[i];
    ushort4 h; unsigned short dummy;
    f32_split(v.x, h.x, dummy); f32_split(v.y, h.y, dummy);
    f32_split(v.z, h.z, dummy); f32_split(v.w, h.w, dummy);
    ((ushort4*)xh)[i] = h;
}

// ---------------------------------------------------------------------------
// K0w: W[k][n] f32 -> WhT[n][k], WlT[n][k]  (f16 bits, scaled x1024), 64x64 tiles
// ---------------------------------------------------------------------------
__global__ __launch_bounds__(256)
void k0_convw(const float* __restrict__ W, unsigned short* __restrict__ WhT,
              unsigned short* __restrict__ WlT)
{
    __shared__ float t[64][65];
    const int tid = threadIdx.x;
    const int k0 = blockIdx.x * 64;
    const int n0 = blockIdx.y * 64;
#pragma unroll
    for (int i = 0; i < 16; ++i) {
        int idx = i * 256 + tid;
        int r = idx >> 6, c = idx & 63;
        t[r][c] = W[(size_t)(k0 + r) * NCOL + n0 + c];
    }
    __syncthreads();
#pragma unroll
    for (int i = 0; i < 8; ++i) {
        int idx = i * 256 + tid;
        int n = idx >> 5, kp = idx & 31;
        float a = t[2 * kp][n]     * 1024.0f;
        float b = t[2 * kp + 1][n] * 1024.0f;
        unsigned short ah, al, bh, bl;
        f32_split(a, ah, al);
        f32_split(b, bh, bl);
        unsigned int wh = (unsigned)ah | ((unsigned)bh << 16);
        unsigned int wl = (unsigned)al | ((unsigned)bl << 16);
        size_t row = (size_t)(n0 + n) * DIM + k0;
        *(unsigned int*)(WhT + row + 2 * kp) = wh;
        *(unsigned int*)(WlT + row + 2 * kp) = wl;
    }
}

// ---------------------------------------------------------------------------
// K1: f16 MFMA approx logits + fused per-(token, slab) top-12.
// 512 thr (8 waves, 2x4 of 64x64 tiles), tile 128 tok x 256 cols/chunk, BK=32.
// Round-4 K-loop (STAGE-before-wait, vmcnt(6/3/0), dual barrier) +
// round-6 conflict-free swizzle + prefiltered scalar scan.
// 72KB LDS -> 2 blocks/CU.
// ---------------------------------------------------------------------------
__global__ __launch_bounds__(512, 4)
void k1_mfma(const unsigned short* __restrict__ xh,
             const unsigned short* __restrict__ WhT,
             float* __restrict__ part_s, int* __restrict__ part_i)
{
    // 3 staging buffers @ b*24576: A[128][32]f16 (8KB) + B[256][32]f16 (16KB)
    // swizzle: LDS slot (row, j) holds global k-octet j ^ ((row>>1)&3)
    // sel f32[128][132] (67.6KB) aliases staging (dead during selection)
    __shared__ __align__(16) unsigned char smem[73728];

    const int tid  = threadIdx.x;
    const int lane = tid & 63;
    const int wave = tid >> 6;
    const int wr = wave >> 2;        // 0..1 : 64-row half
    const int wc = wave & 3;         // 0..3 : 64-col group
    const int slab = blockIdx.x;     // 0..15
    const int tokbase = blockIdx.y * BM;

    // staging: thread covers (row = tid>>2, slot = tid&3); global oct pre-swizzled
    const int srow = tid >> 2;
    const int soct = (tid & 3) ^ ((tid >> 3) & 3);   // (tid&3) ^ ((row>>1)&3)
    const unsigned short* pA = xh + (size_t)(tokbase + srow) * DIM + soct * 8;

    // frag reads: oct slot = (lane>>4) ^ ((c4>>1)&3)   [row = tile*16 + c4]
    const int c4 = lane & 15;
    const int xj = (((lane >> 4) ^ ((c4 >> 1) & 3)) << 4);
    const int offA0 =        (wr * 64 + c4) * 64 + xj;   // + m*1024
    const int offB0 = 8192 + (wc * 64 + c4) * 64 + xj;   // + n*1024

    float ts[CKS]; int ti[CKS];
#pragma unroll
    for (int k = 0; k < CKS; ++k) { ts[k] = -INFINITY; ti[k] = 0x7fffffff; }

    float* sel = (float*)smem;

    #define STAGE(pb, buf, kk) do {                                              \
        unsigned b_ = (unsigned)(buf) * 24576u + (unsigned)wave * 1024u;         \
        gll16(pA   + (size_t)(kk) * BK,                smem + b_);               \
        gll16((pb) + (size_t)(kk) * BK,                smem + b_ + 8192);        \
        gll16((pb) + (size_t)128 * DIM + (kk) * BK,    smem + b_ + 16384);       \
    } while (0)

    // insertion of one scalar (strict >: later/higher idx loses ties)
    #define INS1(v_, ci_) do {                                                    \
        if ((v_) > ts[CKS - 1]) {                                                 \
            float cv = (v_); int ci = (ci_);                                      \
            _Pragma("unroll")                                                     \
            for (int k = 0; k < CKS; ++k) {                                       \
                bool g = cv > ts[k];                                              \
                float os = ts[k]; int oi = ti[k];                                 \
                ts[k] = g ? cv : os; ti[k] = g ? ci : oi;                         \
                cv = g ? os : cv;   ci = g ? oi : ci;                             \
            }                                                                     \
        }                                                                         \
    } while (0)

#pragma unroll 1
    for (int nc = 0; nc < NCHUNK; ++nc) {
        const int n0 = slab * SLABCOLS + nc * BN;
        const unsigned short* pB = WhT + (size_t)(n0 + srow) * DIM + soct * 8;

        f32x4 acc[4][4];
        const f32x4 zero = {0.f, 0.f, 0.f, 0.f};
#pragma unroll
        for (int m = 0; m < 4; ++m)
#pragma unroll
            for (int n = 0; n < 4; ++n) acc[m][n] = zero;

        STAGE(pB, 0, 0);
        STAGE(pB, 1, 1);

#pragma unroll 1
        for (int kk = 0; kk < KSTEPS; ++kk) {
            if (kk < KSTEPS - 2) {
                STAGE(pB, (kk + 2) % 3, kk + 2);
                WAITVM_(6);                  // stage kk landed; kk+1,kk+2 in flight
            } else if (kk == KSTEPS - 2) {
                WAITVM_(3);
            } else {
                WAITVM_(0);
            }
            __builtin_amdgcn_s_barrier();

            const unsigned char* bp = smem + (unsigned)(kk % 3) * 24576u;
            f16x8 Af[4];
#pragma unroll
            for (int m = 0; m < 4; ++m) Af[m] = *(const f16x8*)(bp + offA0 + m * 1024);
#pragma unroll
            for (int n = 0; n < 4; ++n) {
                f16x8 Bf = *(const f16x8*)(bp + offB0 + n * 1024);
#pragma unroll
                for (int m = 0; m < 4; ++m)
                    acc[m][n] = __builtin_amdgcn_mfma_f32_16x16x32_f16(Af[m], Bf, acc[m][n], 0, 0, 0);
            }

            WAITLGKM0;                       // my frag reads done before others overwrite
            __builtin_amdgcn_s_barrier();
        }

        // ---- selection: 2 phases of 128 cols; prefiltered scalar scan ----
#pragma unroll 1
        for (int p = 0; p < 2; ++p) {
            if ((wc >> 1) == p) {
                const int colb = (wc & 1) * 64;
#pragma unroll
                for (int m = 0; m < 4; ++m)
#pragma unroll
                    for (int n = 0; n < 4; ++n) {
                        const int col = colb + n * 16 + c4;
                        const int row = wr * 64 + m * 16 + (lane >> 4) * 4;
#pragma unroll
                        for (int r = 0; r < 4; ++r)
                            sel[(row + r) * SELSTRIDE + col] = acc[m][n][r];
                    }
            }
            __syncthreads();
            {
                // thread scans cols part, part+4, ..., part+124 of its token
                const int part = tid & 3;
                const float* rp = sel + (tid >> 2) * SELSTRIDE + part;
                const int ibase = n0 + p * 128 + part;
#pragma unroll 1
                for (int j = 0; j < 8; ++j) {
                    float a0 = rp[16 * j];
                    float a1 = rp[16 * j + 4];
                    float a2 = rp[16 * j + 8];
                    float a3 = rp[16 * j + 12];
                    float mx = fmaxf(fmaxf(a0, a1), fmaxf(a2, a3));
                    if (mx > ts[CKS - 1]) {
                        INS1(a0, ibase + 16 * j);
                        INS1(a1, ibase + 16 * j + 4);
                        INS1(a2, ibase + 16 * j + 8);
                        INS1(a3, ibase + 16 * j + 12);
                    }
                }
            }
            __syncthreads();
        }
    }
    #undef STAGE

    // ---- merge the 4 per-part lists per token -> slab top-12 ----
    float* Ls = (float*)smem;                 // 512*12*4 = 24576
    int*   Li = (int*)(smem + 24576);
#pragma unroll
    for (int k = 0; k < CKS; ++k) {
        Ls[tid * CKS + k] = ts[k];
        Li[tid * CKS + k] = ti[k];
    }
    __syncthreads();
    if (tid < BM) {
        const int b0 = (tid * 4 + 0) * CKS, b1 = (tid * 4 + 1) * CKS;
        const int b2 = (tid * 4 + 2) * CKS, b3 = (tid * 4 + 3) * CKS;
        int h0 = 0, h1 = 0, h2 = 0, h3 = 0;
        const size_t ob = ((size_t)(tokbase + tid) * SLABS + slab) * CKS;
#pragma unroll 1
        for (int k = 0; k < CKS; ++k) {
            float s0 = Ls[b0 + h0]; int i0 = Li[b0 + h0];
            float s1 = Ls[b1 + h1]; int i1 = Li[b1 + h1];
            float s2 = Ls[b2 + h2]; int i2 = Li[b2 + h2];
            float s3 = Ls[b3 + h3]; int i3 = Li[b3 + h3];
            float bs = s0; int bi = i0; int bp = 0;
            if (s1 > bs || (s1 == bs && i1 < bi)) { bs = s1; bi = i1; bp = 1; }
            if (s2 > bs || (s2 == bs && i2 < bi)) { bs = s2; bi = i2; bp = 2; }
            if (s3 > bs || (s3 == bs && i3 < bi)) { bs = s3; bi = i3; bp = 3; }
            part_s[ob + k] = bs; part_i[ob + k] = bi;
            if      (bp == 0) ++h0;
            else if (bp == 1) ++h1;
            else if (bp == 2) ++h2;
            else              ++h3;
        }
    }
}

// ---------------------------------------------------------------------------
// K3: merge 192 approx partials -> approx top-32 pool -> exact rescore
// (f32 x, split-f16 W reconstruction) -> exact top-20 -> fine stage.
// ---------------------------------------------------------------------------
__global__ __launch_bounds__(256)
void k3_fine(const float* __restrict__ x, const float* __restrict__ Wenc,
             const float* __restrict__ Kall, const float* __restrict__ Vall,
             const unsigned short* __restrict__ WhT, const unsigned short* __restrict__ WlT,
             const float* __restrict__ part_s, const int* __restrict__ part_i,
             float* __restrict__ out)
{
    const int tok = blockIdx.x;
    const int tid = threadIdx.x;

    __shared__ float xs[DIM];
    __shared__ float qs[RANK];
    __shared__ float ls[NPART];
    __shared__ int   li[NPART];
    __shared__ int   pool[POOL];
    __shared__ float resc[POOL];
    __shared__ int   cand[CK];
    __shared__ float fsc[CK];
    __shared__ float fss[FK];
    __shared__ int   fgi[FK];
    __shared__ float fw[FK];

    ((float4*)xs)[tid] = ((const float4*)(x + (size_t)tok * DIM))[tid];
    if (tid < NPART) {
        ls[tid] = part_s[(size_t)tok * NPART + tid];
        li[tid] = part_i[(size_t)tok * NPART + tid];
    }
    __syncthreads();

    // approx top-32 of 192 via lex rank (idx distinct -> unique ranks)
    if (tid < NPART) {
        float s = ls[tid]; int idx = li[tid];
        int r = 0;
        for (int e = 0; e < NPART; ++e) {
            float s2 = ls[e]; int i2 = li[e];
            r += (s2 > s) || (s2 == s && i2 < idx);
        }
        if (r < POOL) pool[r] = idx;
    }
    __syncthreads();

    // exact rescore of 32 pooled candidates: 8 threads per candidate
    {
        const int c = tid >> 3, oct = tid & 7;
        const int idx = pool[c];
        const ushort4* ph = (const ushort4*)(WhT + (size_t)idx * DIM + oct * 128);
        const ushort4* pl = (const ushort4*)(WlT + (size_t)idx * DIM + oct * 128);
        const float* xp = xs + oct * 128;
        float a = 0.0f;
#pragma unroll 4
        for (int j = 0; j < 32; ++j) {
            ushort4 hv = ph[j], lv = pl[j];
            a = fmaf(xp[j*4+0], (float)__builtin_bit_cast(f16, hv.x) + (float)__builtin_bit_cast(f16, lv.x), a);
            a = fmaf(xp[j*4+1], (float)__builtin_bit_cast(f16, hv.y) + (float)__builtin_bit_cast(f16, lv.y), a);
            a = fmaf(xp[j*4+2], (float)__builtin_bit_cast(f16, hv.z) + (float)__builtin_bit_cast(f16, lv.z), a);
            a = fmaf(xp[j*4+3], (float)__builtin_bit_cast(f16, hv.w) + (float)__builtin_bit_cast(f16, lv.w), a);
        }
        a += __shfl_down(a, 4, 8);
        a += __shfl_down(a, 2, 8);
        a += __shfl_down(a, 1, 8);
        if (oct == 0) resc[c] = a * (1.0f / 1024.0f);   // undo x1024 W scale (exact)
    }
    __syncthreads();

    // exact top-20 of 32 rescored (lex: score desc, idx asc)
    if (tid < POOL) {
        float s = resc[tid]; int idx = pool[tid];
        int r = 0;
        for (int e = 0; e < POOL; ++e)
            r += (resc[e] > s) || (resc[e] == s && pool[e] < idx);
        if (r < CK) cand[r] = idx;
    }
    __syncthreads();

    // query = x . W_enc
    if (tid < RANK) {
        float q = 0.0f;
#pragma unroll 8
        for (int d = 0; d < DIM; ++d)
            q = fmaf(xs[d], Wenc[(size_t)d * RANK + tid], q);
        qs[tid] = q;
    }
    __syncthreads();

    if (tid < CK) {
        const float* Kr = Kall + (size_t)cand[tid] * RANK;
        float s = 0.0f;
#pragma unroll 8
        for (int r = 0; r < RANK; ++r) s = fmaf(qs[r], Kr[r], s);
        fsc[tid] = s * 0.08838834764831845f;   // 1/sqrt(128)
    }
    __syncthreads();

    if (tid < CK) {
        float s = fsc[tid]; int r = 0;
        for (int e = 0; e < CK; ++e)
            r += (fsc[e] > s) || (fsc[e] == s && e < tid);
        if (r < FK) { fss[r] = s; fgi[r] = cand[tid]; }
    }
    __syncthreads();

    if (tid == 0) {
        float m = fss[0];
#pragma unroll
        for (int k = 1; k < FK; ++k) m = fmaxf(m, fss[k]);
        float w[FK]; float sum = 0.0f;
#pragma unroll
        for (int k = 0; k < FK; ++k) { w[k] = expf(fss[k] - m); sum += w[k]; }
        float inv = 1.0f / sum;
#pragma unroll
        for (int k = 0; k < FK; ++k) fw[k] = w[k] * inv;
    }
    __syncthreads();

#pragma unroll
    for (int jj = 0; jj < DIM / 256; ++jj) {
        const int d = tid + jj * 256;
        float o = 0.0f;
#pragma unroll
        for (int f = 0; f < FK; ++f)
            o = fmaf(fw[f], Vall[(size_t)fgi[f] * DIM + d], o);
        out[(size_t)tok * DIM + d] = o;
    }
}

// ---------------------------------------------------------------------------
// Fallback path (round-1, f32 VALU): proven correct if ws is too small.
// ---------------------------------------------------------------------------
__global__ __launch_bounds__(256, 2)
void k1_router_f32(const float* __restrict__ x, const float* __restrict__ Wr,
                   float* __restrict__ part_s, int* __restrict__ part_i)
{
    __shared__ float smem[64][257];
    const int tid     = threadIdx.x;
    const int tokbase = blockIdx.x * 64;
    const int colbase = blockIdx.y * 8192;
    const int mytok   = tid & 63;
    const int mypart  = tid >> 6;

    float ts[CK]; int ti[CK];
#pragma unroll
    for (int k = 0; k < CK; ++k) { ts[k] = -INFINITY; ti[k] = 0x7fffffff; }

#pragma unroll 1
    for (int cg = 0; cg < 32; ++cg) {
        const int n = colbase + cg * 256 + tid;
        float acc[64];
#pragma unroll
        for (int t = 0; t < 64; ++t) acc[t] = 0.0f;
#pragma unroll 1
        for (int dc = 0; dc < DIM; dc += 8) {
            float w[8];
#pragma unroll
            for (int i = 0; i < 8; ++i)
                w[i] = Wr[(size_t)(dc + i) * NCOL + n];
#pragma unroll
            for (int t = 0; t < 64; ++t) {
                const float* xr = x + (size_t)(tokbase + t) * DIM + dc;
#pragma unroll
                for (int i = 0; i < 8; ++i)
                    acc[t] = fmaf(xr[i], w[i], acc[t]);
            }
        }
        __syncthreads();
#pragma unroll
        for (int t = 0; t < 64; ++t) smem[t][tid] = acc[t];
        __syncthreads();
        const int jbase = mypart * 64;
#pragma unroll 1
        for (int j = 0; j < 64; ++j) {
            float v = smem[mytok][jbase + j];
            if (v > ts[CK - 1]) {
                float cv = v; int ci = colbase + cg * 256 + jbase + j;
#pragma unroll
                for (int k = 0; k < CK; ++k) {
                    bool g = cv > ts[k];
                    float os = ts[k]; int oi = ti[k];
                    ts[k] = g ? cv : os; ti[k] = g ? ci : oi;
                    cv = g ? os : cv;   ci = g ? oi : ci;
                }
            }
        }
    }
    __syncthreads();
    float* Ls = &smem[0][0];
    int*   Li = (int*)(Ls + 256 * CK);
#pragma unroll
    for (int k = 0; k < CK; ++k) { Ls[tid * CK + k] = ts[k]; Li[tid * CK + k] = ti[k]; }
    __syncthreads();
    if (tid < 64) {
        const int tok = tid;
        int h0 = 0, h1 = 0, h2 = 0, h3 = 0;
        const size_t ob = ((size_t)(tokbase + tok) * 8 + blockIdx.y) * CK;
#pragma unroll 1
        for (int k = 0; k < CK; ++k) {
            float s0 = Ls[(      tok) * CK + h0]; int i0 = Li[(      tok) * CK + h0];
            float s1 = Ls[( 64 + tok) * CK + h1]; int i1 = Li[( 64 + tok) * CK + h1];
            float s2 = Ls[(128 + tok) * CK + h2]; int i2 = Li[(128 + tok) * CK + h2];
            float s3 = Ls[(192 + tok) * CK + h3]; int i3 = Li[(192 + tok) * CK + h3];
            float bs = s0; int bi = i0; int bp = 0;
            if (s1 > bs || (s1 == bs && i1 < bi)) { bs = s1; bi = i1; bp = 1; }
            if (s2 > bs || (s2 == bs && i2 < bi)) { bs = s2; bi = i2; bp = 2; }
            if (s3 > bs || (s3 == bs && i3 < bi)) { bs = s3; bi = i3; bp = 3; }
            part_s[ob + k] = bs; part_i[ob + k] = bi;
            if      (bp == 0) ++h0;
            else if (bp == 1) ++h1;
            else if (bp == 2) ++h2;
            else              ++h3;
        }
    }
}

template<int CT, int BLK>
__global__ __launch_bounds__(BLK)
void k3_fine_direct(const float* __restrict__ x, const float* __restrict__ Wenc,
                    const float* __restrict__ Kall, const float* __restrict__ Vall,
                    const float* __restrict__ part_s, const int* __restrict__ part_i,
                    float* __restrict__ out)
{
    const int tok = blockIdx.x;
    const int tid = threadIdx.x;

    __shared__ float xs[DIM];
    __shared__ float qs[RANK];
    __shared__ float ls[CT * CK];
    __shared__ int   li[CT * CK];
    __shared__ int   cand[CK];
    __shared__ float fsc[CK];
    __shared__ float fss[FK];
    __shared__ int   fgi[FK];
    __shared__ float fw[FK];

    if (tid < DIM / 4)
        ((float4*)xs)[tid] = ((const float4*)(x + (size_t)tok * DIM))[tid];
    for (int i = tid; i < CT * CK; i += BLK) {
        ls[i] = part_s[(size_t)tok * (CT * CK) + i];
        li[i] = part_i[(size_t)tok * (CT * CK) + i];
    }
    __syncthreads();

    if (tid < CT * CK) {
        float s = ls[tid]; int idx = li[tid];
        int r = 0;
        for (int e = 0; e < CT * CK; ++e) {
            float s2 = ls[e]; int i2 = li[e];
            r += (s2 > s) || (s2 == s && i2 < idx);
        }
        if (r < CK) cand[r] = idx;
    }
    __syncthreads();

    if (tid < RANK) {
        float q = 0.0f;
#pragma unroll 8
        for (int d = 0; d < DIM; ++d)
            q = fmaf(xs[d], Wenc[(size_t)d * RANK + tid], q);
        qs[tid] = q;
    }
    __syncthreads();

    if (tid < CK) {
        const float* Kr = Kall + (size_t)cand[tid] * RANK;
        float s = 0.0f;
#pragma unroll 8
        for (int r = 0; r < RANK; ++r) s = fmaf(qs[r], Kr[r], s);
        fsc[tid] = s * 0.08838834764831845f;
    }
    __syncthreads();

    if (tid < CK) {
        float s = fsc[tid]; int r = 0;
        for (int e = 0; e < CK; ++e)
            r += (fsc[e] > s) || (fsc[e] == s && e < tid);
        if (r < FK) { fss[r] = s; fgi[r] = cand[tid]; }
    }
    __syncthreads();

    if (tid == 0) {
        float m = fss[0];
#pragma unroll
        for (int k = 1; k < FK; ++k) m = fmaxf(m, fss[k]);
        float w[FK]; float sum = 0.0f;
#pragma unroll
        for (int k = 0; k < FK; ++k) { w[k] = expf(fss[k] - m); sum += w[k]; }
        float inv = 1.0f / sum;
#pragma unroll
        for (int k = 0; k < FK; ++k) fw[k] = w[k] * inv;
    }
    __syncthreads();

    for (int d = tid; d < DIM; d += BLK) {
        float o = 0.0f;
#pragma unroll
        for (int f = 0; f < FK; ++f)
            o = fmaf(fw[f], Vall[(size_t)fgi[f] * DIM + d], o);
        out[(size_t)tok * DIM + d] = o;
    }
}

extern "C" void kernel_launch(void* const* d_in, const int* in_sizes, int n_in,
                              void* d_out, int out_size, void* d_ws, size_t ws_size,
                              hipStream_t stream)
{
    (void)in_sizes; (void)n_in; (void)out_size;
    const float* x    = (const float*)d_in[0];
    const float* Wr   = (const float*)d_in[1];
    const float* Wenc = (const float*)d_in[2];
    const float* Kall = (const float*)d_in[3];
    const float* Vall = (const float*)d_in[4];
    float* out = (float*)d_out;

    const size_t off_ps = 0;
    const size_t off_pi = off_ps + (size_t)NTOK * NPART * 4;
    const size_t off_xh = off_pi + (size_t)NTOK * NPART * 4;
    const size_t off_wh = off_xh + (size_t)NTOK * DIM * 2;
    const size_t off_wl = off_wh + (size_t)NCOL * DIM * 2;
    const size_t REQ    = off_wl + (size_t)NCOL * DIM * 2;   // ~270 MiB

    if (ws_size >= REQ) {
        float* part_s = (float*)((char*)d_ws + off_ps);
        int*   part_i = (int*)((char*)d_ws + off_pi);
        unsigned short* xh  = (unsigned short*)((char*)d_ws + off_xh);
        unsigned short* WhT = (unsigned short*)((char*)d_ws + off_wh);
        unsigned short* WlT = (unsigned short*)((char*)d_ws + off_wl);

        k0_convx<<<NTOK * DIM / 1024, 256, 0, stream>>>(x, xh);
        k0_convw<<<dim3(DIM / 64, NCOL / 64), 256, 0, stream>>>(Wr, WhT, WlT);
        k1_mfma<<<dim3(SLABS, NTOK / BM), 512, 0, stream>>>(xh, WhT, part_s, part_i);
        k3_fine<<<NTOK, 256, 0, stream>>>(x, Wenc, Kall, Vall, WhT, WlT, part_s, part_i, out);
    } else {
        float* part_s = (float*)d_ws;
        int*   part_i = (int*)d_ws + (size_t)NTOK * 8 * CK;
        k1_router_f32<<<dim3(NTOK / 64, 8), 256, 0, stream>>>(x, Wr, part_s, part_i);
        k3_fine_direct<8, 256><<<NTOK, 256, 0, stream>>>(x, Wenc, Kall, Vall, part_s, part_i, out);
    }
}

// Round 8
// 1261.997 us; speedup vs baseline: 1.3369x; 1.1450x over previous
//
#include <hip/hip_runtime.h>
#include <math.h>
#include <stdint.h>

#define NTOK 4096
#define DIM  1024
#define NCOL 65536
#define RANK 128
#define CK 20
#define FK 10

// ---- Path A (MFMA) geometry ----
#define SLABS 16
#define SLABCOLS (NCOL / SLABS)      // 4096
#define BM 128
#define BN 256
#define BK 32
#define NCHUNK (SLABCOLS / BN)       // 16
#define KSTEPS (DIM / BK)            // 32
#define CKS 12                       // per-slab list length
#define NPART (SLABS * CKS)          // 192
#define POOL 32
#define SELSTRIDE 132                // f32; rows 528B; 2-way banks on scan

typedef _Float16 f16;
typedef __attribute__((ext_vector_type(8))) _Float16 f16x8;
typedef __attribute__((ext_vector_type(4))) float f32x4;

__device__ __forceinline__ void f32_split(float v, unsigned short& h, unsigned short& l) {
    f16 hh = (f16)v;
    float r = v - (float)hh;
    f16 ll = (f16)r;
    h = __builtin_bit_cast(unsigned short, hh);
    l = __builtin_bit_cast(unsigned short, ll);
}

__device__ __forceinline__ void gll16(const void* src, void* ldsdst) {
    __builtin_amdgcn_global_load_lds(
        (__attribute__((address_space(1))) unsigned int*)src,
        (__attribute__((address_space(3))) unsigned int*)ldsdst, 16, 0, 0);
}

#define WAITVM_(n) asm volatile("s_waitcnt vmcnt(" #n ")" ::: "memory")
#define WAITLGKM0  asm volatile("s_waitcnt lgkmcnt(0)" ::: "memory")

// ---------------------------------------------------------------------------
// K0x: x -> f16 hi plane only (A operand), layout [t][k]
// ---------------------------------------------------------------------------
__global__ __launch_bounds__(256)
void k0_convx(const float* __restrict__ x, unsigned short* __restrict__ xh)
{
    int i = blockIdx.x * 256 + threadIdx.x;   // float4 index
    float4 v = ((const float4*)x)[i];
    ushort4 h; unsigned short dummy;
    f32_split(v.x, h.x, dummy); f32_split(v.y, h.y, dummy);
    f32_split(v.z, h.z, dummy); f32_split(v.w, h.w, dummy);
    ((ushort4*)xh)[i] = h;
}

// ---------------------------------------------------------------------------
// K0w: W[k][n] f32 -> WhT[n][k], WlT[n][k]  (f16 bits, scaled x1024), 64x64 tiles
// ---------------------------------------------------------------------------
__global__ __launch_bounds__(256)
void k0_convw(const float* __restrict__ W, unsigned short* __restrict__ WhT,
              unsigned short* __restrict__ WlT)
{
    __shared__ float t[64][65];
    const int tid = threadIdx.x;
    const int k0 = blockIdx.x * 64;
    const int n0 = blockIdx.y * 64;
#pragma unroll
    for (int i = 0; i < 16; ++i) {
        int idx = i * 256 + tid;
        int r = idx >> 6, c = idx & 63;
        t[r][c] = W[(size_t)(k0 + r) * NCOL + n0 + c];
    }
    __syncthreads();
#pragma unroll
    for (int i = 0; i < 8; ++i) {
        int idx = i * 256 + tid;
        int n = idx >> 5, kp = idx & 31;
        float a = t[2 * kp][n]     * 1024.0f;
        float b = t[2 * kp + 1][n] * 1024.0f;
        unsigned short ah, al, bh, bl;
        f32_split(a, ah, al);
        f32_split(b, bh, bl);
        unsigned int wh = (unsigned)ah | ((unsigned)bh << 16);
        unsigned int wl = (unsigned)al | ((unsigned)bl << 16);
        size_t row = (size_t)(n0 + n) * DIM + k0;
        *(unsigned int*)(WhT + row + 2 * kp) = wh;
        *(unsigned int*)(WlT + row + 2 * kp) = wl;
    }
}

// ---------------------------------------------------------------------------
// K1: f16 MFMA approx logits + fused per-(token, slab) top-12.
// Round-4 base (register-clean, V64+A64): 512 thr (8 waves, 2x4 of 64x64
// tiles), 128 tok x 256 cols/chunk, BK=32, 3 staging buffers (24KB).
// CHANGE vs R4: single barrier per K-step. Safe because staging is 1-ahead
// into buf (kk+1)%3 == buffer read at kk-2, closed by BARRIER(kk-1) which
// precedes the stage issue in program order.
// 72KB LDS -> 2 blocks/CU.
// ---------------------------------------------------------------------------
__global__ __launch_bounds__(512, 4)
void k1_mfma(const unsigned short* __restrict__ xh,
             const unsigned short* __restrict__ WhT,
             float* __restrict__ part_s, int* __restrict__ part_i)
{
    // 3 staging buffers @ b*24576: A[128][32]f16 (8KB) + B[256][32]f16 (16KB)
    // swizzle (R4): LDS slot (row, j) holds global k-octet j ^ (row&3)
    // sel f32[128][132] (67.6KB) aliases staging (dead during selection)
    __shared__ __align__(16) unsigned char smem[73728];

    const int tid  = threadIdx.x;
    const int lane = tid & 63;
    const int wave = tid >> 6;
    const int wr = wave >> 2;        // 0..1 : 64-row half
    const int wc = wave & 3;         // 0..3 : 64-col group
    const int slab = blockIdx.x;     // 0..15
    const int tokbase = blockIdx.y * BM;

    // staging: thread covers (row = tid>>2, slot = tid&3); global oct pre-swizzled
    const int srow = tid >> 2;
    const int soct = (tid & 3) ^ ((tid >> 2) & 3);   // R4: ^(row&3)
    const unsigned short* pA = xh + (size_t)(tokbase + srow) * DIM + soct * 8;

    // frag reads (R4): oct slot = (lane>>4) ^ (c4&3)   [row = tile*16 + c4]
    const int c4 = lane & 15;
    const int xj = (((lane >> 4) ^ (lane & 3)) << 4);
    const int offA0 =        (wr * 64 + c4) * 64 + xj;   // + m*1024
    const int offB0 = 8192 + (wc * 64 + c4) * 64 + xj;   // + n*1024

    float ts[CKS]; int ti[CKS];
#pragma unroll
    for (int k = 0; k < CKS; ++k) { ts[k] = -INFINITY; ti[k] = 0x7fffffff; }

    float* sel = (float*)smem;

    #define STAGE(pb, buf, kk) do {                                              \
        unsigned b_ = (unsigned)(buf) * 24576u + (unsigned)wave * 1024u;         \
        gll16(pA   + (size_t)(kk) * BK,                smem + b_);               \
        gll16((pb) + (size_t)(kk) * BK,                smem + b_ + 8192);        \
        gll16((pb) + (size_t)128 * DIM + (kk) * BK,    smem + b_ + 16384);       \
    } while (0)

    // insertion of one scalar (strict >: later/higher idx loses ties)
    #define INS1(v_, ci_) do {                                                    \
        if ((v_) > ts[CKS - 1]) {                                                 \
            float cv = (v_); int ci = (ci_);                                      \
            _Pragma("unroll")                                                     \
            for (int k = 0; k < CKS; ++k) {                                       \
                bool g = cv > ts[k];                                              \
                float os = ts[k]; int oi = ti[k];                                 \
                ts[k] = g ? cv : os; ti[k] = g ? ci : oi;                         \
                cv = g ? os : cv;   ci = g ? oi : ci;                             \
            }                                                                     \
        }                                                                         \
    } while (0)

#pragma unroll 1
    for (int nc = 0; nc < NCHUNK; ++nc) {
        const int n0 = slab * SLABCOLS + nc * BN;
        const unsigned short* pB = WhT + (size_t)(n0 + srow) * DIM + soct * 8;

        f32x4 acc[4][4];
        const f32x4 zero = {0.f, 0.f, 0.f, 0.f};
#pragma unroll
        for (int m = 0; m < 4; ++m)
#pragma unroll
            for (int n = 0; n < 4; ++n) acc[m][n] = zero;

        STAGE(pB, 0, 0);

#pragma unroll 1
        for (int kk = 0; kk < KSTEPS; ++kk) {
            if (kk + 1 < KSTEPS) {
                STAGE(pB, (kk + 1) % 3, kk + 1);   // targets buf read at kk-2
                WAITVM_(3);                        // stage kk landed; kk+1 in flight
            } else {
                WAITVM_(0);
            }
            __builtin_amdgcn_s_barrier();          // single barrier per step

            const unsigned char* bp = smem + (unsigned)(kk % 3) * 24576u;
            f16x8 Af[4];
#pragma unroll
            for (int m = 0; m < 4; ++m) Af[m] = *(const f16x8*)(bp + offA0 + m * 1024);
#pragma unroll
            for (int n = 0; n < 4; ++n) {
                f16x8 Bf = *(const f16x8*)(bp + offB0 + n * 1024);
#pragma unroll
                for (int m = 0; m < 4; ++m)
                    acc[m][n] = __builtin_amdgcn_mfma_f32_16x16x32_f16(Af[m], Bf, acc[m][n], 0, 0, 0);
            }

            WAITLGKM0;                 // my frag reads done before next barrier
        }
        __builtin_amdgcn_s_barrier();  // close kk=31 reads before sel overwrite

        // ---- selection: 2 phases of 128 cols; plain scalar scan (R4) ----
#pragma unroll 1
        for (int p = 0; p < 2; ++p) {
            if ((wc >> 1) == p) {
                const int colb = (wc & 1) * 64;
#pragma unroll
                for (int m = 0; m < 4; ++m)
#pragma unroll
                    for (int n = 0; n < 4; ++n) {
                        const int col = colb + n * 16 + c4;
                        const int row = wr * 64 + m * 16 + (lane >> 4) * 4;
#pragma unroll
                        for (int r = 0; r < 4; ++r)
                            sel[(row + r) * SELSTRIDE + col] = acc[m][n][r];
                    }
            }
            __syncthreads();
            {
                // thread scans cols part, part+4, ..., part+124 of its token
                const int part = tid & 3;
                const float* rp = sel + (tid >> 2) * SELSTRIDE + part;
                const int ibase = n0 + p * 128 + part;
#pragma unroll 1
                for (int j = 0; j < 32; ++j) {
                    float v = rp[4 * j];
                    INS1(v, ibase + 4 * j);
                }
            }
            __syncthreads();
        }
    }
    #undef STAGE

    // ---- merge the 4 per-part lists per token -> slab top-12 ----
    float* Ls = (float*)smem;                 // 512*12*4 = 24576
    int*   Li = (int*)(smem + 24576);
#pragma unroll
    for (int k = 0; k < CKS; ++k) {
        Ls[tid * CKS + k] = ts[k];
        Li[tid * CKS + k] = ti[k];
    }
    __syncthreads();
    if (tid < BM) {
        const int b0 = (tid * 4 + 0) * CKS, b1 = (tid * 4 + 1) * CKS;
        const int b2 = (tid * 4 + 2) * CKS, b3 = (tid * 4 + 3) * CKS;
        int h0 = 0, h1 = 0, h2 = 0, h3 = 0;
        const size_t ob = ((size_t)(tokbase + tid) * SLABS + slab) * CKS;
#pragma unroll 1
        for (int k = 0; k < CKS; ++k) {
            float s0 = Ls[b0 + h0]; int i0 = Li[b0 + h0];
            float s1 = Ls[b1 + h1]; int i1 = Li[b1 + h1];
            float s2 = Ls[b2 + h2]; int i2 = Li[b2 + h2];
            float s3 = Ls[b3 + h3]; int i3 = Li[b3 + h3];
            float bs = s0; int bi = i0; int bp = 0;
            if (s1 > bs || (s1 == bs && i1 < bi)) { bs = s1; bi = i1; bp = 1; }
            if (s2 > bs || (s2 == bs && i2 < bi)) { bs = s2; bi = i2; bp = 2; }
            if (s3 > bs || (s3 == bs && i3 < bi)) { bs = s3; bi = i3; bp = 3; }
            part_s[ob + k] = bs; part_i[ob + k] = bi;
            if      (bp == 0) ++h0;
            else if (bp == 1) ++h1;
            else if (bp == 2) ++h2;
            else              ++h3;
        }
    }
}

// ---------------------------------------------------------------------------
// K3: merge 192 approx partials -> approx top-32 pool -> exact rescore
// (f32 x, split-f16 W reconstruction) -> exact top-20 -> fine stage.
// ---------------------------------------------------------------------------
__global__ __launch_bounds__(256)
void k3_fine(const float* __restrict__ x, const float* __restrict__ Wenc,
             const float* __restrict__ Kall, const float* __restrict__ Vall,
             const unsigned short* __restrict__ WhT, const unsigned short* __restrict__ WlT,
             const float* __restrict__ part_s, const int* __restrict__ part_i,
             float* __restrict__ out)
{
    const int tok = blockIdx.x;
    const int tid = threadIdx.x;

    __shared__ float xs[DIM];
    __shared__ float qs[RANK];
    __shared__ float ls[NPART];
    __shared__ int   li[NPART];
    __shared__ int   pool[POOL];
    __shared__ float resc[POOL];
    __shared__ int   cand[CK];
    __shared__ float fsc[CK];
    __shared__ float fss[FK];
    __shared__ int   fgi[FK];
    __shared__ float fw[FK];

    ((float4*)xs)[tid] = ((const float4*)(x + (size_t)tok * DIM))[tid];
    if (tid < NPART) {
        ls[tid] = part_s[(size_t)tok * NPART + tid];
        li[tid] = part_i[(size_t)tok * NPART + tid];
    }
    __syncthreads();

    // approx top-32 of 192 via lex rank (idx distinct -> unique ranks)
    if (tid < NPART) {
        float s = ls[tid]; int idx = li[tid];
        int r = 0;
        for (int e = 0; e < NPART; ++e) {
            float s2 = ls[e]; int i2 = li[e];
            r += (s2 > s) || (s2 == s && i2 < idx);
        }
        if (r < POOL) pool[r] = idx;
    }
    __syncthreads();

    // exact rescore of 32 pooled candidates: 8 threads per candidate
    {
        const int c = tid >> 3, oct = tid & 7;
        const int idx = pool[c];
        const ushort4* ph = (const ushort4*)(WhT + (size_t)idx * DIM + oct * 128);
        const ushort4* pl = (const ushort4*)(WlT + (size_t)idx * DIM + oct * 128);
        const float* xp = xs + oct * 128;
        float a = 0.0f;
#pragma unroll 4
        for (int j = 0; j < 32; ++j) {
            ushort4 hv = ph[j], lv = pl[j];
            a = fmaf(xp[j*4+0], (float)__builtin_bit_cast(f16, hv.x) + (float)__builtin_bit_cast(f16, lv.x), a);
            a = fmaf(xp[j*4+1], (float)__builtin_bit_cast(f16, hv.y) + (float)__builtin_bit_cast(f16, lv.y), a);
            a = fmaf(xp[j*4+2], (float)__builtin_bit_cast(f16, hv.z) + (float)__builtin_bit_cast(f16, lv.z), a);
            a = fmaf(xp[j*4+3], (float)__builtin_bit_cast(f16, hv.w) + (float)__builtin_bit_cast(f16, lv.w), a);
        }
        a += __shfl_down(a, 4, 8);
        a += __shfl_down(a, 2, 8);
        a += __shfl_down(a, 1, 8);
        if (oct == 0) resc[c] = a * (1.0f / 1024.0f);   // undo x1024 W scale (exact)
    }
    __syncthreads();

    // exact top-20 of 32 rescored (lex: score desc, idx asc)
    if (tid < POOL) {
        float s = resc[tid]; int idx = pool[tid];
        int r = 0;
        for (int e = 0; e < POOL; ++e)
            r += (resc[e] > s) || (resc[e] == s && pool[e] < idx);
        if (r < CK) cand[r] = idx;
    }
    __syncthreads();

    // query = x . W_enc
    if (tid < RANK) {
        float q = 0.0f;
#pragma unroll 8
        for (int d = 0; d < DIM; ++d)
            q = fmaf(xs[d], Wenc[(size_t)d * RANK + tid], q);
        qs[tid] = q;
    }
    __syncthreads();

    if (tid < CK) {
        const float* Kr = Kall + (size_t)cand[tid] * RANK;
        float s = 0.0f;
#pragma unroll 8
        for (int r = 0; r < RANK; ++r) s = fmaf(qs[r], Kr[r], s);
        fsc[tid] = s * 0.08838834764831845f;   // 1/sqrt(128)
    }
    __syncthreads();

    if (tid < CK) {
        float s = fsc[tid]; int r = 0;
        for (int e = 0; e < CK; ++e)
            r += (fsc[e] > s) || (fsc[e] == s && e < tid);
        if (r < FK) { fss[r] = s; fgi[r] = cand[tid]; }
    }
    __syncthreads();

    if (tid == 0) {
        float m = fss[0];
#pragma unroll
        for (int k = 1; k < FK; ++k) m = fmaxf(m, fss[k]);
        float w[FK]; float sum = 0.0f;
#pragma unroll
        for (int k = 0; k < FK; ++k) { w[k] = expf(fss[k] - m); sum += w[k]; }
        float inv = 1.0f / sum;
#pragma unroll
        for (int k = 0; k < FK; ++k) fw[k] = w[k] * inv;
    }
    __syncthreads();

#pragma unroll
    for (int jj = 0; jj < DIM / 256; ++jj) {
        const int d = tid + jj * 256;
        float o = 0.0f;
#pragma unroll
        for (int f = 0; f < FK; ++f)
            o = fmaf(fw[f], Vall[(size_t)fgi[f] * DIM + d], o);
        out[(size_t)tok * DIM + d] = o;
    }
}

// ---------------------------------------------------------------------------
// Fallback path (round-1, f32 VALU): proven correct if ws is too small.
// ---------------------------------------------------------------------------
__global__ __launch_bounds__(256, 2)
void k1_router_f32(const float* __restrict__ x, const float* __restrict__ Wr,
                   float* __restrict__ part_s, int* __restrict__ part_i)
{
    __shared__ float smem[64][257];
    const int tid     = threadIdx.x;
    const int tokbase = blockIdx.x * 64;
    const int colbase = blockIdx.y * 8192;
    const int mytok   = tid & 63;
    const int mypart  = tid >> 6;

    float ts[CK]; int ti[CK];
#pragma unroll
    for (int k = 0; k < CK; ++k) { ts[k] = -INFINITY; ti[k] = 0x7fffffff; }

#pragma unroll 1
    for (int cg = 0; cg < 32; ++cg) {
        const int n = colbase + cg * 256 + tid;
        float acc[64];
#pragma unroll
        for (int t = 0; t < 64; ++t) acc[t] = 0.0f;
#pragma unroll 1
        for (int dc = 0; dc < DIM; dc += 8) {
            float w[8];
#pragma unroll
            for (int i = 0; i < 8; ++i)
                w[i] = Wr[(size_t)(dc + i) * NCOL + n];
#pragma unroll
            for (int t = 0; t < 64; ++t) {
                const float* xr = x + (size_t)(tokbase + t) * DIM + dc;
#pragma unroll
                for (int i = 0; i < 8; ++i)
                    acc[t] = fmaf(xr[i], w[i], acc[t]);
            }
        }
        __syncthreads();
#pragma unroll
        for (int t = 0; t < 64; ++t) smem[t][tid] = acc[t];
        __syncthreads();
        const int jbase = mypart * 64;
#pragma unroll 1
        for (int j = 0; j < 64; ++j) {
            float v = smem[mytok][jbase + j];
            if (v > ts[CK - 1]) {
                float cv = v; int ci = colbase + cg * 256 + jbase + j;
#pragma unroll
                for (int k = 0; k < CK; ++k) {
                    bool g = cv > ts[k];
                    float os = ts[k]; int oi = ti[k];
                    ts[k] = g ? cv : os; ti[k] = g ? ci : oi;
                    cv = g ? os : cv;   ci = g ? oi : ci;
                }
            }
        }
    }
    __syncthreads();
    float* Ls = &smem[0][0];
    int*   Li = (int*)(Ls + 256 * CK);
#pragma unroll
    for (int k = 0; k < CK; ++k) { Ls[tid * CK + k] = ts[k]; Li[tid * CK + k] = ti[k]; }
    __syncthreads();
    if (tid < 64) {
        const int tok = tid;
        int h0 = 0, h1 = 0, h2 = 0, h3 = 0;
        const size_t ob = ((size_t)(tokbase + tok) * 8 + blockIdx.y) * CK;
#pragma unroll 1
        for (int k = 0; k < CK; ++k) {
            float s0 = Ls[(      tok) * CK + h0]; int i0 = Li[(      tok) * CK + h0];
            float s1 = Ls[( 64 + tok) * CK + h1]; int i1 = Li[( 64 + tok) * CK + h1];
            float s2 = Ls[(128 + tok) * CK + h2]; int i2 = Li[(128 + tok) * CK + h2];
            float s3 = Ls[(192 + tok) * CK + h3]; int i3 = Li[(192 + tok) * CK + h3];
            float bs = s0; int bi = i0; int bp = 0;
            if (s1 > bs || (s1 == bs && i1 < bi)) { bs = s1; bi = i1; bp = 1; }
            if (s2 > bs || (s2 == bs && i2 < bi)) { bs = s2; bi = i2; bp = 2; }
            if (s3 > bs || (s3 == bs && i3 < bi)) { bs = s3; bi = i3; bp = 3; }
            part_s[ob + k] = bs; part_i[ob + k] = bi;
            if      (bp == 0) ++h0;
            else if (bp == 1) ++h1;
            else if (bp == 2) ++h2;
            else              ++h3;
        }
    }
}

template<int CT, int BLK>
__global__ __launch_bounds__(BLK)
void k3_fine_direct(const float* __restrict__ x, const float* __restrict__ Wenc,
                    const float* __restrict__ Kall, const float* __restrict__ Vall,
                    const float* __restrict__ part_s, const int* __restrict__ part_i,
                    float* __restrict__ out)
{
    const int tok = blockIdx.x;
    const int tid = threadIdx.x;

    __shared__ float xs[DIM];
    __shared__ float qs[RANK];
    __shared__ float ls[CT * CK];
    __shared__ int   li[CT * CK];
    __shared__ int   cand[CK];
    __shared__ float fsc[CK];
    __shared__ float fss[FK];
    __shared__ int   fgi[FK];
    __shared__ float fw[FK];

    if (tid < DIM / 4)
        ((float4*)xs)[tid] = ((const float4*)(x + (size_t)tok * DIM))[tid];
    for (int i = tid; i < CT * CK; i += BLK) {
        ls[i] = part_s[(size_t)tok * (CT * CK) + i];
        li[i] = part_i[(size_t)tok * (CT * CK) + i];
    }
    __syncthreads();

    if (tid < CT * CK) {
        float s = ls[tid]; int idx = li[tid];
        int r = 0;
        for (int e = 0; e < CT * CK; ++e) {
            float s2 = ls[e]; int i2 = li[e];
            r += (s2 > s) || (s2 == s && i2 < idx);
        }
        if (r < CK) cand[r] = idx;
    }
    __syncthreads();

    if (tid < RANK) {
        float q = 0.0f;
#pragma unroll 8
        for (int d = 0; d < DIM; ++d)
            q = fmaf(xs[d], Wenc[(size_t)d * RANK + tid], q);
        qs[tid] = q;
    }
    __syncthreads();

    if (tid < CK) {
        const float* Kr = Kall + (size_t)cand[tid] * RANK;
        float s = 0.0f;
#pragma unroll 8
        for (int r = 0; r < RANK; ++r) s = fmaf(qs[r], Kr[r], s);
        fsc[tid] = s * 0.08838834764831845f;
    }
    __syncthreads();

    if (tid < CK) {
        float s = fsc[tid]; int r = 0;
        for (int e = 0; e < CK; ++e)
            r += (fsc[e] > s) || (fsc[e] == s && e < tid);
        if (r < FK) { fss[r] = s; fgi[r] = cand[tid]; }
    }
    __syncthreads();

    if (tid == 0) {
        float m = fss[0];
#pragma unroll
        for (int k = 1; k < FK; ++k) m = fmaxf(m, fss[k]);
        float w[FK]; float sum = 0.0f;
#pragma unroll
        for (int k = 0; k < FK; ++k) { w[k] = expf(fss[k] - m); sum += w[k]; }
        float inv = 1.0f / sum;
#pragma unroll
        for (int k = 0; k < FK; ++k) fw[k] = w[k] * inv;
    }
    __syncthreads();

    for (int d = tid; d < DIM; d += BLK) {
        float o = 0.0f;
#pragma unroll
        for (int f = 0; f < FK; ++f)
            o = fmaf(fw[f], Vall[(size_t)fgi[f] * DIM + d], o);
        out[(size_t)tok * DIM + d] = o;
    }
}

extern "C" void kernel_launch(void* const* d_in, const int* in_sizes, int n_in,
                              void* d_out, int out_size, void* d_ws, size_t ws_size,
                              hipStream_t stream)
{
    (void)in_sizes; (void)n_in; (void)out_size;
    const float* x    = (const float*)d_in[0];
    const float* Wr   = (const float*)d_in[1];
    const float* Wenc = (const float*)d_in[2];
    const float* Kall = (const float*)d_in[3];
    const float* Vall = (const float*)d_in[4];
    float* out = (float*)d_out;

    const size_t off_ps = 0;
    const size_t off_pi = off_ps + (size_t)NTOK * NPART * 4;
    const size_t off_xh = off_pi + (size_t)NTOK * NPART * 4;
    const size_t off_wh = off_xh + (size_t)NTOK * DIM * 2;
    const size_t off_wl = off_wh + (size_t)NCOL * DIM * 2;
    const size_t REQ    = off_wl + (size_t)NCOL * DIM * 2;   // ~270 MiB

    if (ws_size >= REQ) {
        float* part_s = (float*)((char*)d_ws + off_ps);
        int*   part_i = (int*)((char*)d_ws + off_pi);
        unsigned short* xh  = (unsigned short*)((char*)d_ws + off_xh);
        unsigned short* WhT = (unsigned short*)((char*)d_ws + off_wh);
        unsigned short* WlT = (unsigned short*)((char*)d_ws + off_wl);

        k0_convx<<<NTOK * DIM / 1024, 256, 0, stream>>>(x, xh);
        k0_convw<<<dim3(DIM / 64, NCOL / 64), 256, 0, stream>>>(Wr, WhT, WlT);
        k1_mfma<<<dim3(SLABS, NTOK / BM), 512, 0, stream>>>(xh, WhT, part_s, part_i);
        k3_fine<<<NTOK, 256, 0, stream>>>(x, Wenc, Kall, Vall, WhT, WlT, part_s, part_i, out);
    } else {
        float* part_s = (float*)d_ws;
        int*   part_i = (int*)d_ws + (size_t)NTOK * 8 * CK;
        k1_router_f32<<<dim3(NTOK / 64, 8), 256, 0, stream>>>(x, Wr, part_s, part_i);
        k3_fine_direct<8, 256><<<NTOK, 256, 0, stream>>>(x, Wenc, Kall, Vall, part_s, part_i, out);
    }
}

// Round 9
// 1252.477 us; speedup vs baseline: 1.3471x; 1.0076x over previous
//
#include <hip/hip_runtime.h>
#include <math.h>
#include <stdint.h>

#define NTOK 4096
#define DIM  1024
#define NCOL 65536
#define RANK 128
#define CK 20
#define FK 10

// ---- Path A (MFMA) geometry ----
#define SLABS 16
#define SLABCOLS (NCOL / SLABS)      // 4096
#define BM 128
#define BN 256
#define BK 32
#define NCHUNK (SLABCOLS / BN)       // 16
#define KSTEPS (DIM / BK)            // 32
#define CKS 12                       // per-slab list length
#define NPART (SLABS * CKS)          // 192
#define POOL 32
#define SELSTRIDE 132                // f32; rows 528B; 2-way banks on scan

typedef _Float16 f16;
typedef __attribute__((ext_vector_type(8))) _Float16 f16x8;
typedef __attribute__((ext_vector_type(4))) float f32x4;

__device__ __forceinline__ void f32_split(float v, unsigned short& h, unsigned short& l) {
    f16 hh = (f16)v;
    float r = v - (float)hh;
    f16 ll = (f16)r;
    h = __builtin_bit_cast(unsigned short, hh);
    l = __builtin_bit_cast(unsigned short, ll);
}

__device__ __forceinline__ void gll16(const void* src, void* ldsdst) {
    __builtin_amdgcn_global_load_lds(
        (__attribute__((address_space(1))) unsigned int*)src,
        (__attribute__((address_space(3))) unsigned int*)ldsdst, 16, 0, 0);
}

#define WAITVM_(n) asm volatile("s_waitcnt vmcnt(" #n ")" ::: "memory")
#define WAITLGKM0  asm volatile("s_waitcnt lgkmcnt(0)" ::: "memory")

// ---------------------------------------------------------------------------
// K0x: x -> f16 hi plane only (A operand), layout [t][k]
// ---------------------------------------------------------------------------
__global__ __launch_bounds__(256)
void k0_convx(const float* __restrict__ x, unsigned short* __restrict__ xh)
{
    int i = blockIdx.x * 256 + threadIdx.x;   // float4 index
    float4 v = ((const float4*)x)[i];
    ushort4 h; unsigned short dummy;
    f32_split(v.x, h.x, dummy); f32_split(v.y, h.y, dummy);
    f32_split(v.z, h.z, dummy); f32_split(v.w, h.w, dummy);
    ((ushort4*)xh)[i] = h;
}

// ---------------------------------------------------------------------------
// K0w: W[k][n] f32 -> WhT[n][k], WlT[n][k]  (f16 bits, scaled x1024), 64x64 tiles
// ---------------------------------------------------------------------------
__global__ __launch_bounds__(256)
void k0_convw(const float* __restrict__ W, unsigned short* __restrict__ WhT,
              unsigned short* __restrict__ WlT)
{
    __shared__ float t[64][65];
    const int tid = threadIdx.x;
    const int k0 = blockIdx.x * 64;
    const int n0 = blockIdx.y * 64;
#pragma unroll
    for (int i = 0; i < 16; ++i) {
        int idx = i * 256 + tid;
        int r = idx >> 6, c = idx & 63;
        t[r][c] = W[(size_t)(k0 + r) * NCOL + n0 + c];
    }
    __syncthreads();
#pragma unroll
    for (int i = 0; i < 8; ++i) {
        int idx = i * 256 + tid;
        int n = idx >> 5, kp = idx & 31;
        float a = t[2 * kp][n]     * 1024.0f;
        float b = t[2 * kp + 1][n] * 1024.0f;
        unsigned short ah, al, bh, bl;
        f32_split(a, ah, al);
        f32_split(b, bh, bl);
        unsigned int wh = (unsigned)ah | ((unsigned)bh << 16);
        unsigned int wl = (unsigned)al | ((unsigned)bl << 16);
        size_t row = (size_t)(n0 + n) * DIM + k0;
        *(unsigned int*)(WhT + row + 2 * kp) = wh;
        *(unsigned int*)(WlT + row + 2 * kp) = wl;
    }
}

// ---------------------------------------------------------------------------
// K1: f16 MFMA approx logits + fused per-(token, slab) top-12.
// R8 base (register-clean V64+A64, single barrier/K-step, plain scan) +
// R6's conflict-free swizzle (2-way max on frag reads; R8's was 4-way and
// cost ~11% since the kernel is LDS-throughput bound).
// 72KB LDS -> 2 blocks/CU.
// ---------------------------------------------------------------------------
__global__ __launch_bounds__(512, 4)
void k1_mfma(const unsigned short* __restrict__ xh,
             const unsigned short* __restrict__ WhT,
             float* __restrict__ part_s, int* __restrict__ part_i)
{
    // 3 staging buffers @ b*24576: A[128][32]f16 (8KB) + B[256][32]f16 (16KB)
    // swizzle (R6): LDS slot (row, j) holds global k-octet j ^ ((row>>1)&3)
    // sel f32[128][132] (67.6KB) aliases staging (dead during selection)
    __shared__ __align__(16) unsigned char smem[73728];

    const int tid  = threadIdx.x;
    const int lane = tid & 63;
    const int wave = tid >> 6;
    const int wr = wave >> 2;        // 0..1 : 64-row half
    const int wc = wave & 3;         // 0..3 : 64-col group
    const int slab = blockIdx.x;     // 0..15
    const int tokbase = blockIdx.y * BM;

    // staging: thread covers (row = tid>>2, slot = tid&3); global oct pre-swizzled
    const int srow = tid >> 2;
    const int soct = (tid & 3) ^ ((tid >> 3) & 3);   // R6: ^((row>>1)&3)
    const unsigned short* pA = xh + (size_t)(tokbase + srow) * DIM + soct * 8;

    // frag reads (R6): oct slot = (lane>>4) ^ ((c4>>1)&3)  [row = tile*16 + c4]
    const int c4 = lane & 15;
    const int xj = (((lane >> 4) ^ ((c4 >> 1) & 3)) << 4);
    const int offA0 =        (wr * 64 + c4) * 64 + xj;   // + m*1024
    const int offB0 = 8192 + (wc * 64 + c4) * 64 + xj;   // + n*1024

    float ts[CKS]; int ti[CKS];
#pragma unroll
    for (int k = 0; k < CKS; ++k) { ts[k] = -INFINITY; ti[k] = 0x7fffffff; }

    float* sel = (float*)smem;

    #define STAGE(pb, buf, kk) do {                                              \
        unsigned b_ = (unsigned)(buf) * 24576u + (unsigned)wave * 1024u;         \
        gll16(pA   + (size_t)(kk) * BK,                smem + b_);               \
        gll16((pb) + (size_t)(kk) * BK,                smem + b_ + 8192);        \
        gll16((pb) + (size_t)128 * DIM + (kk) * BK,    smem + b_ + 16384);       \
    } while (0)

    // insertion of one scalar (strict >: later/higher idx loses ties)
    #define INS1(v_, ci_) do {                                                    \
        if ((v_) > ts[CKS - 1]) {                                                 \
            float cv = (v_); int ci = (ci_);                                      \
            _Pragma("unroll")                                                     \
            for (int k = 0; k < CKS; ++k) {                                       \
                bool g = cv > ts[k];                                              \
                float os = ts[k]; int oi = ti[k];                                 \
                ts[k] = g ? cv : os; ti[k] = g ? ci : oi;                         \
                cv = g ? os : cv;   ci = g ? oi : ci;                             \
            }                                                                     \
        }                                                                         \
    } while (0)

#pragma unroll 1
    for (int nc = 0; nc < NCHUNK; ++nc) {
        const int n0 = slab * SLABCOLS + nc * BN;
        const unsigned short* pB = WhT + (size_t)(n0 + srow) * DIM + soct * 8;

        f32x4 acc[4][4];
        const f32x4 zero = {0.f, 0.f, 0.f, 0.f};
#pragma unroll
        for (int m = 0; m < 4; ++m)
#pragma unroll
            for (int n = 0; n < 4; ++n) acc[m][n] = zero;

        STAGE(pB, 0, 0);

#pragma unroll 1
        for (int kk = 0; kk < KSTEPS; ++kk) {
            if (kk + 1 < KSTEPS) {
                STAGE(pB, (kk + 1) % 3, kk + 1);   // targets buf read at kk-2
                WAITVM_(3);                        // stage kk landed; kk+1 in flight
            } else {
                WAITVM_(0);
            }
            __builtin_amdgcn_s_barrier();          // single barrier per step

            const unsigned char* bp = smem + (unsigned)(kk % 3) * 24576u;
            f16x8 Af[4];
#pragma unroll
            for (int m = 0; m < 4; ++m) Af[m] = *(const f16x8*)(bp + offA0 + m * 1024);
#pragma unroll
            for (int n = 0; n < 4; ++n) {
                f16x8 Bf = *(const f16x8*)(bp + offB0 + n * 1024);
#pragma unroll
                for (int m = 0; m < 4; ++m)
                    acc[m][n] = __builtin_amdgcn_mfma_f32_16x16x32_f16(Af[m], Bf, acc[m][n], 0, 0, 0);
            }

            WAITLGKM0;                 // my frag reads done before next barrier
        }
        __builtin_amdgcn_s_barrier();  // close kk=31 reads before sel overwrite

        // ---- selection: 2 phases of 128 cols; plain scalar scan ----
#pragma unroll 1
        for (int p = 0; p < 2; ++p) {
            if ((wc >> 1) == p) {
                const int colb = (wc & 1) * 64;
#pragma unroll
                for (int m = 0; m < 4; ++m)
#pragma unroll
                    for (int n = 0; n < 4; ++n) {
                        const int col = colb + n * 16 + c4;
                        const int row = wr * 64 + m * 16 + (lane >> 4) * 4;
#pragma unroll
                        for (int r = 0; r < 4; ++r)
                            sel[(row + r) * SELSTRIDE + col] = acc[m][n][r];
                    }
            }
            __syncthreads();
            {
                // thread scans cols part, part+4, ..., part+124 of its token
                const int part = tid & 3;
                const float* rp = sel + (tid >> 2) * SELSTRIDE + part;
                const int ibase = n0 + p * 128 + part;
#pragma unroll 1
                for (int j = 0; j < 32; ++j) {
                    float v = rp[4 * j];
                    INS1(v, ibase + 4 * j);
                }
            }
            __syncthreads();
        }
    }
    #undef STAGE

    // ---- merge the 4 per-part lists per token -> slab top-12 ----
    float* Ls = (float*)smem;                 // 512*12*4 = 24576
    int*   Li = (int*)(smem + 24576);
#pragma unroll
    for (int k = 0; k < CKS; ++k) {
        Ls[tid * CKS + k] = ts[k];
        Li[tid * CKS + k] = ti[k];
    }
    __syncthreads();
    if (tid < BM) {
        const int b0 = (tid * 4 + 0) * CKS, b1 = (tid * 4 + 1) * CKS;
        const int b2 = (tid * 4 + 2) * CKS, b3 = (tid * 4 + 3) * CKS;
        int h0 = 0, h1 = 0, h2 = 0, h3 = 0;
        const size_t ob = ((size_t)(tokbase + tid) * SLABS + slab) * CKS;
#pragma unroll 1
        for (int k = 0; k < CKS; ++k) {
            float s0 = Ls[b0 + h0]; int i0 = Li[b0 + h0];
            float s1 = Ls[b1 + h1]; int i1 = Li[b1 + h1];
            float s2 = Ls[b2 + h2]; int i2 = Li[b2 + h2];
            float s3 = Ls[b3 + h3]; int i3 = Li[b3 + h3];
            float bs = s0; int bi = i0; int bp = 0;
            if (s1 > bs || (s1 == bs && i1 < bi)) { bs = s1; bi = i1; bp = 1; }
            if (s2 > bs || (s2 == bs && i2 < bi)) { bs = s2; bi = i2; bp = 2; }
            if (s3 > bs || (s3 == bs && i3 < bi)) { bs = s3; bi = i3; bp = 3; }
            part_s[ob + k] = bs; part_i[ob + k] = bi;
            if      (bp == 0) ++h0;
            else if (bp == 1) ++h1;
            else if (bp == 2) ++h2;
            else              ++h3;
        }
    }
}

// ---------------------------------------------------------------------------
// K3: merge 192 approx partials -> approx top-32 pool -> exact rescore
// (f32 x, split-f16 W reconstruction) -> exact top-20 -> fine stage.
// ---------------------------------------------------------------------------
__global__ __launch_bounds__(256)
void k3_fine(const float* __restrict__ x, const float* __restrict__ Wenc,
             const float* __restrict__ Kall, const float* __restrict__ Vall,
             const unsigned short* __restrict__ WhT, const unsigned short* __restrict__ WlT,
             const float* __restrict__ part_s, const int* __restrict__ part_i,
             float* __restrict__ out)
{
    const int tok = blockIdx.x;
    const int tid = threadIdx.x;

    __shared__ float xs[DIM];
    __shared__ float qs[RANK];
    __shared__ float ls[NPART];
    __shared__ int   li[NPART];
    __shared__ int   pool[POOL];
    __shared__ float resc[POOL];
    __shared__ int   cand[CK];
    __shared__ float fsc[CK];
    __shared__ float fss[FK];
    __shared__ int   fgi[FK];
    __shared__ float fw[FK];

    ((float4*)xs)[tid] = ((const float4*)(x + (size_t)tok * DIM))[tid];
    if (tid < NPART) {
        ls[tid] = part_s[(size_t)tok * NPART + tid];
        li[tid] = part_i[(size_t)tok * NPART + tid];
    }
    __syncthreads();

    // approx top-32 of 192 via lex rank (idx distinct -> unique ranks)
    if (tid < NPART) {
        float s = ls[tid]; int idx = li[tid];
        int r = 0;
        for (int e = 0; e < NPART; ++e) {
            float s2 = ls[e]; int i2 = li[e];
            r += (s2 > s) || (s2 == s && i2 < idx);
        }
        if (r < POOL) pool[r] = idx;
    }
    __syncthreads();

    // exact rescore of 32 pooled candidates: 8 threads per candidate
    {
        const int c = tid >> 3, oct = tid & 7;
        const int idx = pool[c];
        const ushort4* ph = (const ushort4*)(WhT + (size_t)idx * DIM + oct * 128);
        const ushort4* pl = (const ushort4*)(WlT + (size_t)idx * DIM + oct * 128);
        const float* xp = xs + oct * 128;
        float a = 0.0f;
#pragma unroll 4
        for (int j = 0; j < 32; ++j) {
            ushort4 hv = ph[j], lv = pl[j];
            a = fmaf(xp[j*4+0], (float)__builtin_bit_cast(f16, hv.x) + (float)__builtin_bit_cast(f16, lv.x), a);
            a = fmaf(xp[j*4+1], (float)__builtin_bit_cast(f16, hv.y) + (float)__builtin_bit_cast(f16, lv.y), a);
            a = fmaf(xp[j*4+2], (float)__builtin_bit_cast(f16, hv.z) + (float)__builtin_bit_cast(f16, lv.z), a);
            a = fmaf(xp[j*4+3], (float)__builtin_bit_cast(f16, hv.w) + (float)__builtin_bit_cast(f16, lv.w), a);
        }
        a += __shfl_down(a, 4, 8);
        a += __shfl_down(a, 2, 8);
        a += __shfl_down(a, 1, 8);
        if (oct == 0) resc[c] = a * (1.0f / 1024.0f);   // undo x1024 W scale (exact)
    }
    __syncthreads();

    // exact top-20 of 32 rescored (lex: score desc, idx asc)
    if (tid < POOL) {
        float s = resc[tid]; int idx = pool[tid];
        int r = 0;
        for (int e = 0; e < POOL; ++e)
            r += (resc[e] > s) || (resc[e] == s && pool[e] < idx);
        if (r < CK) cand[r] = idx;
    }
    __syncthreads();

    // query = x . W_enc
    if (tid < RANK) {
        float q = 0.0f;
#pragma unroll 8
        for (int d = 0; d < DIM; ++d)
            q = fmaf(xs[d], Wenc[(size_t)d * RANK + tid], q);
        qs[tid] = q;
    }
    __syncthreads();

    if (tid < CK) {
        const float* Kr = Kall + (size_t)cand[tid] * RANK;
        float s = 0.0f;
#pragma unroll 8
        for (int r = 0; r < RANK; ++r) s = fmaf(qs[r], Kr[r], s);
        fsc[tid] = s * 0.08838834764831845f;   // 1/sqrt(128)
    }
    __syncthreads();

    if (tid < CK) {
        float s = fsc[tid]; int r = 0;
        for (int e = 0; e < CK; ++e)
            r += (fsc[e] > s) || (fsc[e] == s && e < tid);
        if (r < FK) { fss[r] = s; fgi[r] = cand[tid]; }
    }
    __syncthreads();

    if (tid == 0) {
        float m = fss[0];
#pragma unroll
        for (int k = 1; k < FK; ++k) m = fmaxf(m, fss[k]);
        float w[FK]; float sum = 0.0f;
#pragma unroll
        for (int k = 0; k < FK; ++k) { w[k] = expf(fss[k] - m); sum += w[k]; }
        float inv = 1.0f / sum;
#pragma unroll
        for (int k = 0; k < FK; ++k) fw[k] = w[k] * inv;
    }
    __syncthreads();

#pragma unroll
    for (int jj = 0; jj < DIM / 256; ++jj) {
        const int d = tid + jj * 256;
        float o = 0.0f;
#pragma unroll
        for (int f = 0; f < FK; ++f)
            o = fmaf(fw[f], Vall[(size_t)fgi[f] * DIM + d], o);
        out[(size_t)tok * DIM + d] = o;
    }
}

// ---------------------------------------------------------------------------
// Fallback path (round-1, f32 VALU): proven correct if ws is too small.
// ---------------------------------------------------------------------------
__global__ __launch_bounds__(256, 2)
void k1_router_f32(const float* __restrict__ x, const float* __restrict__ Wr,
                   float* __restrict__ part_s, int* __restrict__ part_i)
{
    __shared__ float smem[64][257];
    const int tid     = threadIdx.x;
    const int tokbase = blockIdx.x * 64;
    const int colbase = blockIdx.y * 8192;
    const int mytok   = tid & 63;
    const int mypart  = tid >> 6;

    float ts[CK]; int ti[CK];
#pragma unroll
    for (int k = 0; k < CK; ++k) { ts[k] = -INFINITY; ti[k] = 0x7fffffff; }

#pragma unroll 1
    for (int cg = 0; cg < 32; ++cg) {
        const int n = colbase + cg * 256 + tid;
        float acc[64];
#pragma unroll
        for (int t = 0; t < 64; ++t) acc[t] = 0.0f;
#pragma unroll 1
        for (int dc = 0; dc < DIM; dc += 8) {
            float w[8];
#pragma unroll
            for (int i = 0; i < 8; ++i)
                w[i] = Wr[(size_t)(dc + i) * NCOL + n];
#pragma unroll
            for (int t = 0; t < 64; ++t) {
                const float* xr = x + (size_t)(tokbase + t) * DIM + dc;
#pragma unroll
                for (int i = 0; i < 8; ++i)
                    acc[t] = fmaf(xr[i], w[i], acc[t]);
            }
        }
        __syncthreads();
#pragma unroll
        for (int t = 0; t < 64; ++t) smem[t][tid] = acc[t];
        __syncthreads();
        const int jbase = mypart * 64;
#pragma unroll 1
        for (int j = 0; j < 64; ++j) {
            float v = smem[mytok][jbase + j];
            if (v > ts[CK - 1]) {
                float cv = v; int ci = colbase + cg * 256 + jbase + j;
#pragma unroll
                for (int k = 0; k < CK; ++k) {
                    bool g = cv > ts[k];
                    float os = ts[k]; int oi = ti[k];
                    ts[k] = g ? cv : os; ti[k] = g ? ci : oi;
                    cv = g ? os : cv;   ci = g ? oi : ci;
                }
            }
        }
    }
    __syncthreads();
    float* Ls = &smem[0][0];
    int*   Li = (int*)(Ls + 256 * CK);
#pragma unroll
    for (int k = 0; k < CK; ++k) { Ls[tid * CK + k] = ts[k]; Li[tid * CK + k] = ti[k]; }
    __syncthreads();
    if (tid < 64) {
        const int tok = tid;
        int h0 = 0, h1 = 0, h2 = 0, h3 = 0;
        const size_t ob = ((size_t)(tokbase + tok) * 8 + blockIdx.y) * CK;
#pragma unroll 1
        for (int k = 0; k < CK; ++k) {
            float s0 = Ls[(      tok) * CK + h0]; int i0 = Li[(      tok) * CK + h0];
            float s1 = Ls[( 64 + tok) * CK + h1]; int i1 = Li[( 64 + tok) * CK + h1];
            float s2 = Ls[(128 + tok) * CK + h2]; int i2 = Li[(128 + tok) * CK + h2];
            float s3 = Ls[(192 + tok) * CK + h3]; int i3 = Li[(192 + tok) * CK + h3];
            float bs = s0; int bi = i0; int bp = 0;
            if (s1 > bs || (s1 == bs && i1 < bi)) { bs = s1; bi = i1; bp = 1; }
            if (s2 > bs || (s2 == bs && i2 < bi)) { bs = s2; bi = i2; bp = 2; }
            if (s3 > bs || (s3 == bs && i3 < bi)) { bs = s3; bi = i3; bp = 3; }
            part_s[ob + k] = bs; part_i[ob + k] = bi;
            if      (bp == 0) ++h0;
            else if (bp == 1) ++h1;
            else if (bp == 2) ++h2;
            else              ++h3;
        }
    }
}

template<int CT, int BLK>
__global__ __launch_bounds__(BLK)
void k3_fine_direct(const float* __restrict__ x, const float* __restrict__ Wenc,
                    const float* __restrict__ Kall, const float* __restrict__ Vall,
                    const float* __restrict__ part_s, const int* __restrict__ part_i,
                    float* __restrict__ out)
{
    const int tok = blockIdx.x;
    const int tid = threadIdx.x;

    __shared__ float xs[DIM];
    __shared__ float qs[RANK];
    __shared__ float ls[CT * CK];
    __shared__ int   li[CT * CK];
    __shared__ int   cand[CK];
    __shared__ float fsc[CK];
    __shared__ float fss[FK];
    __shared__ int   fgi[FK];
    __shared__ float fw[FK];

    if (tid < DIM / 4)
        ((float4*)xs)[tid] = ((const float4*)(x + (size_t)tok * DIM))[tid];
    for (int i = tid; i < CT * CK; i += BLK) {
        ls[i] = part_s[(size_t)tok * (CT * CK) + i];
        li[i] = part_i[(size_t)tok * (CT * CK) + i];
    }
    __syncthreads();

    if (tid < CT * CK) {
        float s = ls[tid]; int idx = li[tid];
        int r = 0;
        for (int e = 0; e < CT * CK; ++e) {
            float s2 = ls[e]; int i2 = li[e];
            r += (s2 > s) || (s2 == s && i2 < idx);
        }
        if (r < CK) cand[r] = idx;
    }
    __syncthreads();

    if (tid < RANK) {
        float q = 0.0f;
#pragma unroll 8
        for (int d = 0; d < DIM; ++d)
            q = fmaf(xs[d], Wenc[(size_t)d * RANK + tid], q);
        qs[tid] = q;
    }
    __syncthreads();

    if (tid < CK) {
        const float* Kr = Kall + (size_t)cand[tid] * RANK;
        float s = 0.0f;
#pragma unroll 8
        for (int r = 0; r < RANK; ++r) s = fmaf(qs[r], Kr[r], s);
        fsc[tid] = s * 0.08838834764831845f;
    }
    __syncthreads();

    if (tid < CK) {
        float s = fsc[tid]; int r = 0;
        for (int e = 0; e < CK; ++e)
            r += (fsc[e] > s) || (fsc[e] == s && e < tid);
        if (r < FK) { fss[r] = s; fgi[r] = cand[tid]; }
    }
    __syncthreads();

    if (tid == 0) {
        float m = fss[0];
#pragma unroll
        for (int k = 1; k < FK; ++k) m = fmaxf(m, fss[k]);
        float w[FK]; float sum = 0.0f;
#pragma unroll
        for (int k = 0; k < FK; ++k) { w[k] = expf(fss[k] - m); sum += w[k]; }
        float inv = 1.0f / sum;
#pragma unroll
        for (int k = 0; k < FK; ++k) fw[k] = w[k] * inv;
    }
    __syncthreads();

    for (int d = tid; d < DIM; d += BLK) {
        float o = 0.0f;
#pragma unroll
        for (int f = 0; f < FK; ++f)
            o = fmaf(fw[f], Vall[(size_t)fgi[f] * DIM + d], o);
        out[(size_t)tok * DIM + d] = o;
    }
}

extern "C" void kernel_launch(void* const* d_in, const int* in_sizes, int n_in,
                              void* d_out, int out_size, void* d_ws, size_t ws_size,
                              hipStream_t stream)
{
    (void)in_sizes; (void)n_in; (void)out_size;
    const float* x    = (const float*)d_in[0];
    const float* Wr   = (const float*)d_in[1];
    const float* Wenc = (const float*)d_in[2];
    const float* Kall = (const float*)d_in[3];
    const float* Vall = (const float*)d_in[4];
    float* out = (float*)d_out;

    const size_t off_ps = 0;
    const size_t off_pi = off_ps + (size_t)NTOK * NPART * 4;
    const size_t off_xh = off_pi + (size_t)NTOK * NPART * 4;
    const size_t off_wh = off_xh + (size_t)NTOK * DIM * 2;
    const size_t off_wl = off_wh + (size_t)NCOL * DIM * 2;
    const size_t REQ    = off_wl + (size_t)NCOL * DIM * 2;   // ~270 MiB

    if (ws_size >= REQ) {
        float* part_s = (float*)((char*)d_ws + off_ps);
        int*   part_i = (int*)((char*)d_ws + off_pi);
        unsigned short* xh  = (unsigned short*)((char*)d_ws + off_xh);
        unsigned short* WhT = (unsigned short*)((char*)d_ws + off_wh);
        unsigned short* WlT = (unsigned short*)((char*)d_ws + off_wl);

        k0_convx<<<NTOK * DIM / 1024, 256, 0, stream>>>(x, xh);
        k0_convw<<<dim3(DIM / 64, NCOL / 64), 256, 0, stream>>>(Wr, WhT, WlT);
        k1_mfma<<<dim3(SLABS, NTOK / BM), 512, 0, stream>>>(xh, WhT, part_s, part_i);
        k3_fine<<<NTOK, 256, 0, stream>>>(x, Wenc, Kall, Vall, WhT, WlT, part_s, part_i, out);
    } else {
        float* part_s = (float*)d_ws;
        int*   part_i = (int*)d_ws + (size_t)NTOK * 8 * CK;
        k1_router_f32<<<dim3(NTOK / 64, 8), 256, 0, stream>>>(x, Wr, part_s, part_i);
        k3_fine_direct<8, 256><<<NTOK, 256, 0, stream>>>(x, Wenc, Kall, Vall, part_s, part_i, out);
    }
}